// Round 1
// baseline (538.823 us; speedup 1.0000x reference)
//
#include <hip/hip_runtime.h>
#include <hip/hip_bf16.h>
#include <math.h>

#define EMBED 256
#define HIDDEN 128
#define NBATCH 4096
#define HISTN 50
#define KNEAR 10
#define D4 64
#define ITEMN 50000

// ---------------------------------------------------------------------------
// Kernel A: per-item region attention.
// One wave (64 lanes) per item; 4 items per 256-thread block.
// region_out = attn(q=E_in[np[0]], kv=E_out[np])   (with the reshape-key trick)
// region_in  = attn(q=E_out[np[0]], kv=E_in[np])
// ---------------------------------------------------------------------------
__global__ __launch_bounds__(256) void regions_kernel(
    const int* __restrict__ near_pois,
    const float* __restrict__ E_in,
    const float* __restrict__ E_out,
    float* __restrict__ region_in,
    float* __restrict__ region_out)
{
    __shared__ float sIn[4][KNEAR * D4];
    __shared__ float sOut[4][KNEAR * D4];
    const int wave = threadIdx.x >> 6;
    const int lane = threadIdx.x & 63;
    const int n = blockIdx.x * 4 + wave;   // 50000 = 12500*4, always valid

    float* inL = sIn[wave];
    float* outL = sOut[wave];

#pragma unroll
    for (int r = 0; r < KNEAR; ++r) {
        int row = near_pois[n * KNEAR + r];
        inL[r * D4 + lane] = E_in[row * D4 + lane];
        outL[r * D4 + lane] = E_out[row * D4 + lane];
    }
    __syncthreads();

#pragma unroll
    for (int pass = 0; pass < 2; ++pass) {
        // pass 0: q from inL, kv = outL -> region_out
        // pass 1: q from outL, kv = inL -> region_in
        const float* kv = (pass == 0) ? outL : inL;
        const float* qs = (pass == 0) ? inL : outL;
        float q = qs[lane];                 // q[d], d = lane
        float sc[KNEAR];
#pragma unroll
        for (int kk = 0; kk < KNEAR; ++kk) {
            // scores[kk] = sum_d q[d] * kvflat[d*10 + kk]   (reshape, NOT transpose)
            float p = q * kv[lane * KNEAR + kk];
#pragma unroll
            for (int off = 1; off < 64; off <<= 1) p += __shfl_xor(p, off);
            sc[kk] = p * 0.125f;            // / sqrt(64)
        }
        // softmax over 10 (every lane has all scores after butterfly)
        float m = sc[0];
#pragma unroll
        for (int kk = 1; kk < KNEAR; ++kk) m = fmaxf(m, sc[kk]);
        float s = 0.f;
#pragma unroll
        for (int kk = 0; kk < KNEAR; ++kk) { sc[kk] = expf(sc[kk] - m); s += sc[kk]; }
        float inv = 1.f / s;
        float acc = 0.f;
#pragma unroll
        for (int kk = 0; kk < KNEAR; ++kk) acc += sc[kk] * kv[kk * D4 + lane];
        float* dst = (pass == 0) ? region_out : region_in;
        dst[n * D4 + lane] = acc * inv;
    }
}

// ---------------------------------------------------------------------------
// Kernel B: one block (256 thr) per batch element.
//   X[h][e] = hist_vec(h,e) * targ_vec(e)          (50x256 in LDS)
//   H1 = relu(X @ W1^T + b1); score[h] = W2 . H1[h]
//   pred = sum_h w[h] * rowsum(X[h]);  out = sigmoid(pred)
// ---------------------------------------------------------------------------
__global__ __launch_bounds__(256) void score_kernel(
    const int* __restrict__ history,
    const int* __restrict__ target,
    const float* __restrict__ E_hist,
    const float* __restrict__ E_targ,
    const float* __restrict__ region_in,
    const float* __restrict__ region_out,
    const float* __restrict__ W1,
    const float* __restrict__ b1,
    const float* __restrict__ W2,
    float* __restrict__ out)
{
    __shared__ __align__(16) float Xs[HISTN][EMBED];      // 51.2 KB
    __shared__ float Hs[HISTN][HIDDEN + 1];               // 25.8 KB, pad -> no bank conflict
    __shared__ float targS[EMBED];
    __shared__ float rowsum[HISTN];
    __shared__ float scoreS[HISTN];

    const int b = blockIdx.x;
    const int t = threadIdx.x;
    const int lane = t & 63;
    const int wave = t >> 6;

    const int titem = target[b];
    // targ = [E_targ(128) | region_out(64) | region_in(64)]
    if (t < 128)       targS[t] = E_targ[titem * 128 + t];
    else if (t < 192)  targS[t] = region_out[titem * D4 + (t - 128)];
    else               targS[t] = region_in[titem * D4 + (t - 192)];
    __syncthreads();

    const float tg = targS[t];
    // hist = [E_hist(128) | region_in(64) | region_out(64)]
    for (int h = 0; h < HISTN; ++h) {
        int item = history[b * HISTN + h];
        float hv;
        if (t < 128)       hv = E_hist[item * 128 + t];
        else if (t < 192)  hv = region_in[item * D4 + (t - 128)];
        else               hv = region_out[item * D4 + (t - 192)];
        Xs[h][t] = hv * tg;
    }
    __syncthreads();

    // rowsum[h] = sum_e X[h][e]  (= hist[h] . targ)
    for (int h = wave; h < HISTN; h += 4) {
        float p = Xs[h][lane] + Xs[h][lane + 64] + Xs[h][lane + 128] + Xs[h][lane + 192];
#pragma unroll
        for (int off = 1; off < 64; off <<= 1) p += __shfl_xor(p, off);
        if (lane == 0) rowsum[h] = p;
    }

    // matvec: thread (o,g): o = output row, g = which half of e
    const int o = t & 127;
    const int g = t >> 7;
    float acc[HISTN];
#pragma unroll
    for (int h = 0; h < HISTN; ++h) acc[h] = 0.f;

    const float4* W1v = reinterpret_cast<const float4*>(W1 + o * EMBED + g * 128);
    for (int c = 0; c < 32; ++c) {
        float4 w4 = W1v[c];
        const float4* xrow = reinterpret_cast<const float4*>(&Xs[0][g * 128]) + c;
#pragma unroll
        for (int h = 0; h < HISTN; ++h) {
            float4 x4 = *reinterpret_cast<const float4*>(&Xs[h][g * 128 + c * 4]);
            acc[h] += w4.x * x4.x + w4.y * x4.y + w4.z * x4.z + w4.w * x4.w;
        }
        (void)xrow;
    }
    __syncthreads();   // also makes rowsum[] visible later

    if (g == 1) {
        for (int h = 0; h < HISTN; ++h) Hs[h][o] = acc[h];
    }
    __syncthreads();
    if (g == 0) {
        float w2 = W2[o];
        float bb = b1[o];
        for (int h = 0; h < HISTN; ++h) {
            float h1 = acc[h] + Hs[h][o] + bb;
            h1 = fmaxf(h1, 0.f);
            Hs[h][o] = w2 * h1;
        }
    }
    __syncthreads();

    // score[h] = sum_o Hs[h][o]
    for (int h = wave; h < HISTN; h += 4) {
        float p = Hs[h][lane] + Hs[h][lane + 64];
#pragma unroll
        for (int off = 1; off < 64; off <<= 1) p += __shfl_xor(p, off);
        if (lane == 0) scoreS[h] = p;
    }
    __syncthreads();

    if (t == 0) {
        float wv[HISTN];
        float s = 0.f;
        for (int h = 0; h < HISTN; ++h) {
            int item = history[b * HISTN + h];
            float e = (item != titem) ? expf(scoreS[h]) : 0.f;
            wv[h] = e;
            s += e;
        }
        float inv = 1.f / sqrtf(s);       // denom = s^BETA, BETA=0.5
        float pred = 0.f;
        for (int h = 0; h < HISTN; ++h) pred += wv[h] * inv * rowsum[h];
        out[b] = 1.f / (1.f + expf(-pred));
    }
}

extern "C" void kernel_launch(void* const* d_in, const int* in_sizes, int n_in,
                              void* d_out, int out_size, void* d_ws, size_t ws_size,
                              hipStream_t stream) {
    const int* history = (const int*)d_in[0];        // (4096,50)
    const int* target = (const int*)d_in[1];         // (4096,)
    const int* near_pois = (const int*)d_in[2];      // (50000,10)
    // d_in[3] = target_region: unused by reference
    const float* E_in = (const float*)d_in[4];       // (50000,64)
    const float* E_out = (const float*)d_in[5];      // (50000,64)
    const float* E_hist = (const float*)d_in[6];     // (50000,128)
    const float* E_targ = (const float*)d_in[7];     // (50000,128)
    const float* W1 = (const float*)d_in[8];         // (128,256)
    const float* b1 = (const float*)d_in[9];         // (128,)
    const float* W2 = (const float*)d_in[10];        // (1,128)
    float* out = (float*)d_out;                      // (4096,)

    float* region_in = (float*)d_ws;                         // 50000*64 f32
    float* region_out = region_in + (size_t)ITEMN * D4;      // 50000*64 f32

    regions_kernel<<<ITEMN / 4, 256, 0, stream>>>(near_pois, E_in, E_out,
                                                  region_in, region_out);
    score_kernel<<<NBATCH, 256, 0, stream>>>(history, target, E_hist, E_targ,
                                             region_in, region_out, W1, b1, W2, out);
}

// Round 2
// 285.410 us; speedup vs baseline: 1.8879x; 1.8879x over previous
//
#include <hip/hip_runtime.h>
#include <hip/hip_bf16.h>
#include <math.h>

#define EMBED 256
#define HIDDEN 128
#define NBATCH 4096
#define HISTN 50
#define KNEAR 10
#define D4 64
#define ITEMN 50000
#define XSTRIDE 264   // 256 + 8 bf16 pad -> row stride 528B, 2-way LDS conflicts only

typedef __attribute__((ext_vector_type(8))) short short8v;   // 8 bf16 = 4 VGPR
typedef __attribute__((ext_vector_type(4))) float floatx4;

__device__ inline float bf2f(unsigned short u) {
    return __uint_as_float(((unsigned)u) << 16);
}
__device__ inline unsigned short f2bf(float f) {
    union { __hip_bfloat16 h; unsigned short u; } cv;
    cv.h = __float2bfloat16(f);
    return cv.u;
}

// ---------------------------------------------------------------------------
// Kernel P: W1 (128x256 f32) -> bf16, pre-swizzled into MFMA B-fragment order.
// Fragment f = k*8 + nt (k: 8 K-steps of 32, nt: 8 N-tiles of 16).
// Within fragment, lane l, j=0..7: element = W1[nt*16 + (l&15)][k*32 + (l>>4)*8 + j]
// Stored flat so the GEMM's B load is W1f[f*64 + lane] (16B, fully coalesced).
// ---------------------------------------------------------------------------
__global__ __launch_bounds__(256) void prep_w1(const float* __restrict__ W1,
                                               unsigned short* __restrict__ W1s)
{
    int tid = blockIdx.x * 256 + threadIdx.x;   // 0..4095
    int l = tid & 63;
    int f = tid >> 6;
    int k = f >> 3, nt = f & 7;
    int row = nt * 16 + (l & 15);
    int col = k * 32 + ((l >> 4) << 3);
    const float* src = W1 + row * EMBED + col;
#pragma unroll
    for (int j = 0; j < 8; ++j)
        W1s[tid * 8 + j] = f2bf(src[j]);
}

// ---------------------------------------------------------------------------
// Kernel A: per-item region attention (one wave per item), bf16 outputs.
// ---------------------------------------------------------------------------
__global__ __launch_bounds__(256) void regions_kernel(
    const int* __restrict__ near_pois,
    const float* __restrict__ E_in,
    const float* __restrict__ E_out,
    unsigned short* __restrict__ region_in,
    unsigned short* __restrict__ region_out)
{
    __shared__ float sIn[4][KNEAR * D4];
    __shared__ float sOut[4][KNEAR * D4];
    const int wave = threadIdx.x >> 6;
    const int lane = threadIdx.x & 63;
    const int n = blockIdx.x * 4 + wave;   // 50000 = 12500*4

    float* inL = sIn[wave];
    float* outL = sOut[wave];

#pragma unroll
    for (int r = 0; r < KNEAR; ++r) {
        int row = near_pois[n * KNEAR + r];
        inL[r * D4 + lane] = E_in[row * D4 + lane];
        outL[r * D4 + lane] = E_out[row * D4 + lane];
    }
    __syncthreads();

#pragma unroll
    for (int pass = 0; pass < 2; ++pass) {
        const float* kv = (pass == 0) ? outL : inL;
        const float* qs = (pass == 0) ? inL : outL;
        float q = qs[lane];
        float sc[KNEAR];
#pragma unroll
        for (int kk = 0; kk < KNEAR; ++kk) {
            // scores[kk] = sum_d q[d]*kvflat[d*10+kk]   (reshape trick)
            float p = q * kv[lane * KNEAR + kk];
#pragma unroll
            for (int off = 1; off < 64; off <<= 1) p += __shfl_xor(p, off);
            sc[kk] = p * 0.125f;
        }
        float m = sc[0];
#pragma unroll
        for (int kk = 1; kk < KNEAR; ++kk) m = fmaxf(m, sc[kk]);
        float s = 0.f;
#pragma unroll
        for (int kk = 0; kk < KNEAR; ++kk) { sc[kk] = expf(sc[kk] - m); s += sc[kk]; }
        float inv = 1.f / s;
        float acc = 0.f;
#pragma unroll
        for (int kk = 0; kk < KNEAR; ++kk) acc += sc[kk] * kv[kk * D4 + lane];
        unsigned short* dst = (pass == 0) ? region_out : region_in;
        dst[n * D4 + lane] = f2bf(acc * inv);
    }
}

// ---------------------------------------------------------------------------
// Kernel B: 1 block (256 thr, 4 waves) = 2 batch elements.
// X (50x256, bf16) in LDS per batch; GEMM X @ W1^T via mfma 16x16x32 bf16,
// wave w owns M-tile w (rows w*16..w*16+15), all 8 N-tiles, both batches
// (B-fragments loaded once, used twice). f32 epilogue.
// ---------------------------------------------------------------------------
__global__ __launch_bounds__(256) void score_kernel(
    const int* __restrict__ history,
    const int* __restrict__ target,
    const float* __restrict__ E_hist,
    const float* __restrict__ E_targ,
    const unsigned short* __restrict__ Rin,
    const unsigned short* __restrict__ Rout,
    const unsigned short* __restrict__ W1s,
    const float* __restrict__ b1,
    const float* __restrict__ W2,
    float* __restrict__ out)
{
    __shared__ __align__(16) unsigned short Xs[2][64][XSTRIDE];  // 67.6 KB
    __shared__ float targS[EMBED];
    __shared__ float b1S[HIDDEN], W2S[HIDDEN];
    __shared__ float rowsumS[2][HISTN];
    __shared__ float scoreS[2][64];
    __shared__ int sHist[2 * HISTN];
    __shared__ int titemS[2];

    const int t = threadIdx.x;
    const int lane = t & 63;
    const int wv = t >> 6;

    if (t < 128) { b1S[t] = b1[t]; W2S[t] = W2[t]; }
    if (t < 2 * HISTN) sHist[t] = history[blockIdx.x * 2 * HISTN + t];
    if (t < 2) titemS[t] = target[blockIdx.x * 2 + t];
    // zero pad rows 50..63 (read by MFMA A-fragments, must not be garbage)
    {
        const int U64_PER_ROW = XSTRIDE / 4;             // 66
        for (int i = t; i < 2 * 14 * U64_PER_ROW; i += 256) {
            int bb = i / (14 * U64_PER_ROW);
            int rem = i - bb * 14 * U64_PER_ROW;
            ((unsigned long long*)&Xs[bb][50 + rem / U64_PER_ROW][0])[rem % U64_PER_ROW] = 0ull;
        }
    }

    // ---- build X = hist ⊙ targ (bf16) for both batch elements ----
    for (int bb = 0; bb < 2; ++bb) {
        __syncthreads();                       // protect targS reuse
        const int ti = titemS[bb];
        // targ = [E_targ(128) | region_out(64) | region_in(64)]
        if (t < 128)       targS[t] = E_targ[ti * 128 + t];
        else if (t < 192)  targS[t] = bf2f(Rout[ti * D4 + (t - 128)]);
        else               targS[t] = bf2f(Rin[ti * D4 + (t - 192)]);
        __syncthreads();
        const float tg = targS[t];
        // hist = [E_hist(128) | region_in(64) | region_out(64)]
#pragma unroll 10
        for (int h = 0; h < HISTN; ++h) {
            int item = sHist[bb * HISTN + h];
            float hv;
            if (t < 128)       hv = E_hist[item * 128 + t];
            else if (t < 192)  hv = bf2f(Rin[item * D4 + (t - 128)]);
            else               hv = bf2f(Rout[item * D4 + (t - 192)]);
            Xs[bb][h][t] = f2bf(hv * tg);
        }
    }
    __syncthreads();

    // ---- rowsum[h] = sum_e X[h][e] ----
    for (int r = wv; r < 2 * HISTN; r += 4) {
        int bb = r >= HISTN;
        int h = r - bb * HISTN;
        uint2 d = *(const uint2*)&Xs[bb][h][lane * 4];
        float s = __uint_as_float(d.x << 16) + __uint_as_float(d.x & 0xffff0000u)
                + __uint_as_float(d.y << 16) + __uint_as_float(d.y & 0xffff0000u);
#pragma unroll
        for (int off = 1; off < 64; off <<= 1) s += __shfl_xor(s, off);
        if (lane == 0) rowsumS[bb][h] = s;
    }

    // ---- GEMM: H1 = X @ W1^T  (per wave: M-tile wv, 8 N-tiles, 8 K-steps) ----
    floatx4 acc[2][8];
#pragma unroll
    for (int p = 0; p < 2; ++p)
#pragma unroll
        for (int nt = 0; nt < 8; ++nt) acc[p][nt] = (floatx4){0.f, 0.f, 0.f, 0.f};

    const int arow = wv * 16 + (lane & 15);
    const int kl = (lane >> 4) << 3;
    const short8v* W1f = (const short8v*)W1s;
#pragma unroll
    for (int k = 0; k < 8; ++k) {
        short8v a0 = *(const short8v*)&Xs[0][arow][k * 32 + kl];
        short8v a1 = *(const short8v*)&Xs[1][arow][k * 32 + kl];
#pragma unroll
        for (int nt = 0; nt < 8; ++nt) {
            short8v bf = W1f[(k * 8 + nt) * 64 + lane];
            acc[0][nt] = __builtin_amdgcn_mfma_f32_16x16x32_bf16(a0, bf, acc[0][nt], 0, 0, 0);
            acc[1][nt] = __builtin_amdgcn_mfma_f32_16x16x32_bf16(a1, bf, acc[1][nt], 0, 0, 0);
        }
    }

    // ---- epilogue: score[h] = sum_o W2[o]*relu(H1[h][o]+b1[o]) ----
    // D layout: col(o_local) = lane&15, row(h_local) = (lane>>4)*4 + reg
#pragma unroll
    for (int bb = 0; bb < 2; ++bb) {
        float p0 = 0.f, p1 = 0.f, p2 = 0.f, p3 = 0.f;
#pragma unroll
        for (int nt = 0; nt < 8; ++nt) {
            int o = nt * 16 + (lane & 15);
            float bbv = b1S[o], w2 = W2S[o];
            floatx4 a = acc[bb][nt];
            p0 += w2 * fmaxf(a[0] + bbv, 0.f);
            p1 += w2 * fmaxf(a[1] + bbv, 0.f);
            p2 += w2 * fmaxf(a[2] + bbv, 0.f);
            p3 += w2 * fmaxf(a[3] + bbv, 0.f);
        }
        float pr[4] = {p0, p1, p2, p3};
#pragma unroll
        for (int r = 0; r < 4; ++r) {
            float v = pr[r];
            v += __shfl_xor(v, 1); v += __shfl_xor(v, 2);
            v += __shfl_xor(v, 4); v += __shfl_xor(v, 8);
            if ((lane & 15) == 0) {
                int h = wv * 16 + ((lane >> 4) << 2) + r;
                scoreS[bb][h] = v;
            }
        }
    }
    __syncthreads();

    // ---- final: masked exp weighting, pred, sigmoid (wave bb -> batch bb) ----
    if (wv < 2) {
        const int bb = wv;
        const int ti = titemS[bb];
        float e = 0.f, er = 0.f;
        if (lane < HISTN) {
            int item = sHist[bb * HISTN + lane];
            float sc = scoreS[bb][lane];
            e = (item != ti) ? expf(sc) : 0.f;
            er = e * rowsumS[bb][lane];
        }
#pragma unroll
        for (int off = 1; off < 64; off <<= 1) {
            e += __shfl_xor(e, off);
            er += __shfl_xor(er, off);
        }
        if (lane == 0) {
            float pred = er / sqrtf(e);          // denom = (sum e)^0.5
            out[blockIdx.x * 2 + bb] = 1.f / (1.f + expf(-pred));
        }
    }
}

extern "C" void kernel_launch(void* const* d_in, const int* in_sizes, int n_in,
                              void* d_out, int out_size, void* d_ws, size_t ws_size,
                              hipStream_t stream) {
    const int* history = (const int*)d_in[0];        // (4096,50)
    const int* target = (const int*)d_in[1];         // (4096,)
    const int* near_pois = (const int*)d_in[2];      // (50000,10)
    // d_in[3] = target_region: unused by reference
    const float* E_in = (const float*)d_in[4];       // (50000,64)
    const float* E_out = (const float*)d_in[5];      // (50000,64)
    const float* E_hist = (const float*)d_in[6];     // (50000,128)
    const float* E_targ = (const float*)d_in[7];     // (50000,128)
    const float* W1 = (const float*)d_in[8];         // (128,256)
    const float* b1 = (const float*)d_in[9];         // (128,)
    const float* W2 = (const float*)d_in[10];        // (1,128)
    float* out = (float*)d_out;                      // (4096,)

    unsigned short* W1s = (unsigned short*)d_ws;                 // 64 KB
    unsigned short* Rin = W1s + 32768;                           // 6.4 MB
    unsigned short* Rout = Rin + (size_t)ITEMN * D4;             // 6.4 MB

    prep_w1<<<16, 256, 0, stream>>>(W1, W1s);
    regions_kernel<<<ITEMN / 4, 256, 0, stream>>>(near_pois, E_in, E_out, Rin, Rout);
    score_kernel<<<NBATCH / 2, 256, 0, stream>>>(history, target, E_hist, E_targ,
                                                 Rin, Rout, W1s, b1, W2, out);
}

// Round 3
// 146.733 us; speedup vs baseline: 3.6721x; 1.9451x over previous
//
#include <hip/hip_runtime.h>
#include <hip/hip_bf16.h>
#include <math.h>

#define EMBED 256
#define HIDDEN 128
#define NBATCH 4096
#define HISTN 50
#define KNEAR 10
#define D4 64
#define ITEMN 50000
#define XSTRIDE 264   // 256 + 8 bf16 pad -> row stride 528B

typedef __attribute__((ext_vector_type(8))) short short8v;   // 8 bf16 = 4 VGPR
typedef __attribute__((ext_vector_type(4))) float floatx4;

__device__ inline float bf2f(unsigned short u) {
    return __uint_as_float(((unsigned)u) << 16);
}
__device__ inline unsigned short f2bf(float f) {
    union { __hip_bfloat16 h; unsigned short u; } cv;
    cv.h = __float2bfloat16(f);
    return cv.u;
}
__device__ inline unsigned pack2(float a, float b) {
    return (unsigned)f2bf(a) | ((unsigned)f2bf(b) << 16);
}

// ---------------------------------------------------------------------------
// prep_w1: W1 (128x256 f32) -> bf16 MFMA B-fragments (proven layout, round 2).
// fragment f = k*8 + nt; lane l, j: W1[nt*16 + (l&15)][k*32 + (l>>4)*8 + j]
// ---------------------------------------------------------------------------
__global__ __launch_bounds__(256) void prep_w1(const float* __restrict__ W1,
                                               unsigned short* __restrict__ W1s)
{
    int tid = blockIdx.x * 256 + threadIdx.x;   // 0..4095
    int l = tid & 63;
    int f = tid >> 6;
    int k = f >> 3, nt = f & 7;
    int row = nt * 16 + (l & 15);
    int col = k * 32 + ((l >> 4) << 3);
    const float* src = W1 + row * EMBED + col;
#pragma unroll
    for (int j = 0; j < 8; ++j)
        W1s[tid * 8 + j] = f2bf(src[j]);
}

// ---------------------------------------------------------------------------
// cvt_bf16: dense f32 table -> bf16 with dst row stride. 8 elems/thread.
// ---------------------------------------------------------------------------
template<int COLS, int DSTSTRIDE>
__global__ __launch_bounds__(256) void cvt_bf16(const float* __restrict__ src,
                                                unsigned short* __restrict__ dst)
{
    const int perRow = COLS / 8;
    int tid = blockIdx.x * 256 + threadIdx.x;
    int row = tid / perRow;
    int c8 = (tid - row * perRow) * 8;
    if (row >= ITEMN) return;
    const float4* s = (const float4*)&src[(size_t)row * COLS + c8];
    float4 a = s[0], b = s[1];
    uint4 o;
    o.x = pack2(a.x, a.y); o.y = pack2(a.z, a.w);
    o.z = pack2(b.x, b.y); o.w = pack2(b.z, b.w);
    *(uint4*)&dst[(size_t)row * DSTSTRIDE + c8] = o;
}

// ---------------------------------------------------------------------------
// regions: per-item attention, one wave per item. Writes bf16 into rinD/routD
// (strided, so it can write directly into histT's columns when fused).
// ---------------------------------------------------------------------------
template<bool BF16T>
__global__ __launch_bounds__(256) void regions_kernel(
    const int* __restrict__ np,
    const float* __restrict__ EinF, const float* __restrict__ EoutF,
    const unsigned short* __restrict__ EinB, const unsigned short* __restrict__ EoutB,
    unsigned short* __restrict__ rinD, unsigned short* __restrict__ routD, int RS)
{
    __shared__ float sIn[4][KNEAR * D4];
    __shared__ float sOut[4][KNEAR * D4];
    const int wave = threadIdx.x >> 6;
    const int lane = threadIdx.x & 63;
    const int n = blockIdx.x * 4 + wave;   // 50000 = 12500*4

    float* inL = sIn[wave];
    float* outL = sOut[wave];

#pragma unroll
    for (int r = 0; r < KNEAR; ++r) {
        int row = np[n * KNEAR + r];
        if (BF16T) {
            inL[r * D4 + lane] = bf2f(EinB[(size_t)row * D4 + lane]);
            outL[r * D4 + lane] = bf2f(EoutB[(size_t)row * D4 + lane]);
        } else {
            inL[r * D4 + lane] = EinF[(size_t)row * D4 + lane];
            outL[r * D4 + lane] = EoutF[(size_t)row * D4 + lane];
        }
    }
    __syncthreads();

#pragma unroll
    for (int pass = 0; pass < 2; ++pass) {
        const float* kv = (pass == 0) ? outL : inL;
        const float* qs = (pass == 0) ? inL : outL;
        float q = qs[lane];
        float sc[KNEAR];
#pragma unroll
        for (int kk = 0; kk < KNEAR; ++kk) {
            // scores[kk] = sum_d q[d]*kvflat[d*10+kk]   (reshape trick)
            float p = q * kv[lane * KNEAR + kk];
#pragma unroll
            for (int off = 1; off < 64; off <<= 1) p += __shfl_xor(p, off);
            sc[kk] = p * 0.125f;
        }
        float m = sc[0];
#pragma unroll
        for (int kk = 1; kk < KNEAR; ++kk) m = fmaxf(m, sc[kk]);
        float s = 0.f;
#pragma unroll
        for (int kk = 0; kk < KNEAR; ++kk) { sc[kk] = expf(sc[kk] - m); s += sc[kk]; }
        float inv = 1.f / s;
        float acc = 0.f;
#pragma unroll
        for (int kk = 0; kk < KNEAR; ++kk) acc += sc[kk] * kv[kk * D4 + lane];
        unsigned short* dst = (pass == 0) ? routD : rinD;
        dst[(size_t)n * RS + lane] = f2bf(acc * inv);
    }
}

// ---------------------------------------------------------------------------
// score: one block (4 waves) per batch element.
// GEMM: wave owns nt = {2*wv, 2*wv+1}, all 4 M-tiles. rowsum via ones-MFMA.
// ---------------------------------------------------------------------------
template<bool FUSED>
__global__ __launch_bounds__(256, 4) void score_kernel(
    const int* __restrict__ history, const int* __restrict__ target,
    const unsigned short* __restrict__ histT,
    const float* __restrict__ E_hist,
    const unsigned short* __restrict__ rinP, const unsigned short* __restrict__ routP,
    int RS,
    const float* __restrict__ E_targ,
    const unsigned short* __restrict__ W1s,
    const float* __restrict__ b1, const float* __restrict__ W2,
    float* __restrict__ out)
{
    __shared__ __align__(16) unsigned short Xs[64][XSTRIDE];   // 33.8 KB
    __shared__ float scoreP[4][64];
    __shared__ float rowsumS[64];

    const int t = threadIdx.x;
    const int lane = t & 63;
    const int wv = t >> 6;
    const int b = blockIdx.x;
    const int ti = target[b];

    // ---- build X = hist ⊙ targ (bf16) ----
    if (FUSED) {
        const int c4 = lane * 4;               // 4 columns per thread
        float tg0, tg1, tg2, tg3;
        if (c4 < 128) {
            float4 v = *(const float4*)&E_targ[(size_t)ti * 128 + c4];
            tg0 = v.x; tg1 = v.y; tg2 = v.z; tg3 = v.w;
        } else if (c4 < 192) {
            uint2 u = *(const uint2*)&routP[(size_t)ti * RS + (c4 - 128)];
            tg0 = bf2f((unsigned short)(u.x & 0xffff)); tg1 = bf2f((unsigned short)(u.x >> 16));
            tg2 = bf2f((unsigned short)(u.y & 0xffff)); tg3 = bf2f((unsigned short)(u.y >> 16));
        } else {
            uint2 u = *(const uint2*)&rinP[(size_t)ti * RS + (c4 - 192)];
            tg0 = bf2f((unsigned short)(u.x & 0xffff)); tg1 = bf2f((unsigned short)(u.x >> 16));
            tg2 = bf2f((unsigned short)(u.y & 0xffff)); tg3 = bf2f((unsigned short)(u.y >> 16));
        }
#pragma unroll 4
        for (int h = wv; h < HISTN; h += 4) {
            int item = history[b * HISTN + h];          // uniform -> s_load
            uint2 u = *(const uint2*)&histT[(size_t)item * 256 + c4];
            uint2 w;
            w.x = pack2(bf2f((unsigned short)(u.x & 0xffff)) * tg0,
                        bf2f((unsigned short)(u.x >> 16)) * tg1);
            w.y = pack2(bf2f((unsigned short)(u.y & 0xffff)) * tg2,
                        bf2f((unsigned short)(u.y >> 16)) * tg3);
            *(uint2*)&Xs[h][c4] = w;
        }
    } else {
        float tg;
        if (t < 128)       tg = E_targ[(size_t)ti * 128 + t];
        else if (t < 192)  tg = bf2f(routP[(size_t)ti * RS + (t - 128)]);
        else               tg = bf2f(rinP[(size_t)ti * RS + (t - 192)]);
#pragma unroll 10
        for (int h = 0; h < HISTN; ++h) {
            int item = history[b * HISTN + h];
            float hv;
            if (t < 128)       hv = E_hist[(size_t)item * 128 + t];
            else if (t < 192)  hv = bf2f(rinP[(size_t)item * RS + (t - 128)]);
            else               hv = bf2f(routP[(size_t)item * RS + (t - 192)]);
            Xs[h][t] = f2bf(hv * tg);
        }
    }
    // rows 50..63 left uninitialized: they only feed discarded outputs
    // (row i of D depends only on row i of A).
    __syncthreads();

    // ---- GEMM: H1 = X @ W1^T; rowsum via B=ones MFMA ----
    floatx4 acc[4][2];
    floatx4 accr = (floatx4){0.f, 0.f, 0.f, 0.f};
#pragma unroll
    for (int m = 0; m < 4; ++m)
#pragma unroll
        for (int n = 0; n < 2; ++n) acc[m][n] = (floatx4){0.f, 0.f, 0.f, 0.f};

    const int nt0 = wv * 2;
    const int ar = lane & 15;
    const int kl = (lane >> 4) << 3;
    const short8v* W1f = (const short8v*)W1s;
    const short ONE = (short)0x3F80;   // bf16 1.0
    const short8v ones = {ONE, ONE, ONE, ONE, ONE, ONE, ONE, ONE};

#pragma unroll
    for (int k = 0; k < 8; ++k) {
        short8v a0 = *(const short8v*)&Xs[ar][k * 32 + kl];
        short8v a1 = *(const short8v*)&Xs[16 + ar][k * 32 + kl];
        short8v a2 = *(const short8v*)&Xs[32 + ar][k * 32 + kl];
        short8v a3 = *(const short8v*)&Xs[48 + ar][k * 32 + kl];
        short8v ax = *(const short8v*)&Xs[wv * 16 + ar][k * 32 + kl];
        short8v bf0 = W1f[(k * 8 + nt0) * 64 + lane];
        short8v bf1 = W1f[(k * 8 + nt0 + 1) * 64 + lane];
        acc[0][0] = __builtin_amdgcn_mfma_f32_16x16x32_bf16(a0, bf0, acc[0][0], 0, 0, 0);
        acc[0][1] = __builtin_amdgcn_mfma_f32_16x16x32_bf16(a0, bf1, acc[0][1], 0, 0, 0);
        acc[1][0] = __builtin_amdgcn_mfma_f32_16x16x32_bf16(a1, bf0, acc[1][0], 0, 0, 0);
        acc[1][1] = __builtin_amdgcn_mfma_f32_16x16x32_bf16(a1, bf1, acc[1][1], 0, 0, 0);
        acc[2][0] = __builtin_amdgcn_mfma_f32_16x16x32_bf16(a2, bf0, acc[2][0], 0, 0, 0);
        acc[2][1] = __builtin_amdgcn_mfma_f32_16x16x32_bf16(a2, bf1, acc[2][1], 0, 0, 0);
        acc[3][0] = __builtin_amdgcn_mfma_f32_16x16x32_bf16(a3, bf0, acc[3][0], 0, 0, 0);
        acc[3][1] = __builtin_amdgcn_mfma_f32_16x16x32_bf16(a3, bf1, acc[3][1], 0, 0, 0);
        accr      = __builtin_amdgcn_mfma_f32_16x16x32_bf16(ax, ones, accr, 0, 0, 0);
    }

    // rowsum: wave wv owns rows wv*16..wv*16+15 (all D columns identical)
    if (ar == 0) {
        int hb = wv * 16 + ((lane >> 4) << 2);
        rowsumS[hb + 0] = accr[0];
        rowsumS[hb + 1] = accr[1];
        rowsumS[hb + 2] = accr[2];
        rowsumS[hb + 3] = accr[3];
    }

    // ---- epilogue: partial score over this wave's 32 outputs ----
    float w2v[2], b1v[2];
#pragma unroll
    for (int n = 0; n < 2; ++n) {
        int o = (nt0 + n) * 16 + ar;
        w2v[n] = W2[o];
        b1v[n] = b1[o];
    }
#pragma unroll
    for (int m = 0; m < 4; ++m) {
        float p[4] = {0.f, 0.f, 0.f, 0.f};
#pragma unroll
        for (int n = 0; n < 2; ++n)
#pragma unroll
            for (int r = 0; r < 4; ++r)
                p[r] += w2v[n] * fmaxf(acc[m][n][r] + b1v[n], 0.f);
#pragma unroll
        for (int r = 0; r < 4; ++r) {
            float v = p[r];
            v += __shfl_xor(v, 1); v += __shfl_xor(v, 2);
            v += __shfl_xor(v, 4); v += __shfl_xor(v, 8);
            if (ar == 0) scoreP[wv][m * 16 + ((lane >> 4) << 2) + r] = v;
        }
    }
    __syncthreads();

    // ---- final: masked exp weighting, pred, sigmoid ----
    if (wv == 0) {
        float e = 0.f, er = 0.f;
        if (lane < HISTN) {
            int item = history[b * HISTN + lane];
            float sc = scoreP[0][lane] + scoreP[1][lane] + scoreP[2][lane] + scoreP[3][lane];
            e = (item != ti) ? expf(sc) : 0.f;
            er = e * rowsumS[lane];
        }
#pragma unroll
        for (int off = 1; off < 64; off <<= 1) {
            e += __shfl_xor(e, off);
            er += __shfl_xor(er, off);
        }
        if (lane == 0) {
            float pred = er / sqrtf(e);        // denom = (sum e)^0.5
            out[b] = 1.f / (1.f + expf(-pred));
        }
    }
}

extern "C" void kernel_launch(void* const* d_in, const int* in_sizes, int n_in,
                              void* d_out, int out_size, void* d_ws, size_t ws_size,
                              hipStream_t stream) {
    const int* history = (const int*)d_in[0];        // (4096,50)
    const int* target = (const int*)d_in[1];         // (4096,)
    const int* near_pois = (const int*)d_in[2];      // (50000,10)
    // d_in[3] = target_region: unused by reference
    const float* E_in = (const float*)d_in[4];       // (50000,64)
    const float* E_out = (const float*)d_in[5];      // (50000,64)
    const float* E_hist = (const float*)d_in[6];     // (50000,128)
    const float* E_targ = (const float*)d_in[7];     // (50000,128)
    const float* W1 = (const float*)d_in[8];         // (128,256)
    const float* b1 = (const float*)d_in[9];         // (128,)
    const float* W2 = (const float*)d_in[10];        // (1,128)
    float* out = (float*)d_out;                      // (4096,)

    unsigned short* W1s = (unsigned short*)d_ws;     // 64 KB
    unsigned short* base = W1s + 32768;

    const size_t needB = 65536 + (size_t)ITEMN * 256 * 2;                 // histT
    const size_t needA = needB + 2 * (size_t)ITEMN * D4 * 2;              // + EinB/EoutB

    prep_w1<<<16, 256, 0, stream>>>(W1, W1s);

    if (ws_size >= needB) {
        unsigned short* histT = base;                     // [50000][256] bf16
        unsigned short* rinD = histT + 128;               // cols 128..191
        unsigned short* routD = histT + 192;              // cols 192..255
        cvt_bf16<128, 256><<<(ITEMN * 16 + 255) / 256, 256, 0, stream>>>(E_hist, histT);
        if (ws_size >= needA) {
            unsigned short* EinB = histT + (size_t)ITEMN * 256;
            unsigned short* EoutB = EinB + (size_t)ITEMN * D4;
            cvt_bf16<64, 64><<<(ITEMN * 8 + 255) / 256, 256, 0, stream>>>(E_in, EinB);
            cvt_bf16<64, 64><<<(ITEMN * 8 + 255) / 256, 256, 0, stream>>>(E_out, EoutB);
            regions_kernel<true><<<ITEMN / 4, 256, 0, stream>>>(
                near_pois, E_in, E_out, EinB, EoutB, rinD, routD, 256);
        } else {
            regions_kernel<false><<<ITEMN / 4, 256, 0, stream>>>(
                near_pois, E_in, E_out, nullptr, nullptr, rinD, routD, 256);
        }
        score_kernel<true><<<NBATCH, 256, 0, stream>>>(
            history, target, histT, E_hist, rinD, routD, 256,
            E_targ, W1s, b1, W2, out);
    } else {
        // fallback: round-2-proven layout (separate bf16 Rin/Rout, f32 E_hist)
        unsigned short* Rin = base;
        unsigned short* Rout = Rin + (size_t)ITEMN * D4;
        regions_kernel<false><<<ITEMN / 4, 256, 0, stream>>>(
            near_pois, E_in, E_out, nullptr, nullptr, Rin, Rout, D4);
        score_kernel<false><<<NBATCH, 256, 0, stream>>>(
            history, target, nullptr, E_hist, Rin, Rout, D4,
            E_targ, W1s, b1, W2, out);
    }
}

// Round 4
// 97.293 us; speedup vs baseline: 5.5381x; 1.5082x over previous
//
#include <hip/hip_runtime.h>
#include <hip/hip_bf16.h>
#include <math.h>

#define EMBED 256
#define HIDDEN 128
#define NBATCH 4096
#define HISTN 50
#define KNEAR 10
#define D4 64
#define ITEMN 50000
#define XSTRIDE 264   // 256 + 8 bf16 pad -> row stride 528B

typedef __attribute__((ext_vector_type(8))) short short8v;   // 8 bf16 = 4 VGPR
typedef __attribute__((ext_vector_type(4))) float floatx4;

__device__ inline float bf2f(unsigned short u) {
    return __uint_as_float(((unsigned)u) << 16);
}
__device__ inline unsigned short f2bf(float f) {
    union { __hip_bfloat16 h; unsigned short u; } cv;
    cv.h = __float2bfloat16(f);
    return cv.u;
}
__device__ inline unsigned pack2(float a, float b) {
    return (unsigned)f2bf(a) | ((unsigned)f2bf(b) << 16);
}

// DPP helper: combine with lane permuted by CTRL (VALU pipe, no LDS)
template<int CTRL>
__device__ __forceinline__ float dppf(float x) {
    return __uint_as_float((unsigned)__builtin_amdgcn_update_dpp(
        0, (int)__float_as_uint(x), CTRL, 0xF, 0xF, true));
}
#define DPP_XOR1 0xB1        // quad_perm [1,0,3,2]
#define DPP_XOR2 0x4E        // quad_perm [2,3,0,1]
#define DPP_HMIR 0x141       // row_half_mirror
#define DPP_MIR  0x140       // row_mirror

// ---------------------------------------------------------------------------
// prep_w1: W1 (128x256 f32) -> bf16 MFMA B-fragments (proven layout).
// ---------------------------------------------------------------------------
__global__ __launch_bounds__(256) void prep_w1(const float* __restrict__ W1,
                                               unsigned short* __restrict__ W1s)
{
    int tid = blockIdx.x * 256 + threadIdx.x;   // 0..4095
    int l = tid & 63;
    int f = tid >> 6;
    int k = f >> 3, nt = f & 7;
    int row = nt * 16 + (l & 15);
    int col = k * 32 + ((l >> 4) << 3);
    const float* src = W1 + row * EMBED + col;
#pragma unroll
    for (int j = 0; j < 8; ++j)
        W1s[tid * 8 + j] = f2bf(src[j]);
}

// ---------------------------------------------------------------------------
// cvt_bf16: dense f32 table -> bf16 with dst row stride. 8 elems/thread.
// ---------------------------------------------------------------------------
template<int COLS, int DSTSTRIDE>
__global__ __launch_bounds__(256) void cvt_bf16(const float* __restrict__ src,
                                                unsigned short* __restrict__ dst)
{
    const int perRow = COLS / 8;
    int tid = blockIdx.x * 256 + threadIdx.x;
    int row = tid / perRow;
    int c8 = (tid - row * perRow) * 8;
    if (row >= ITEMN) return;
    const float4* s = (const float4*)&src[(size_t)row * COLS + c8];
    float4 a = s[0], b = s[1];
    uint4 o;
    o.x = pack2(a.x, a.y); o.y = pack2(a.z, a.w);
    o.z = pack2(b.x, b.y); o.w = pack2(b.z, b.w);
    *(uint4*)&dst[(size_t)row * DSTSTRIDE + c8] = o;
}

// ---------------------------------------------------------------------------
// regions2: one wave per item, bf16 tables, no block barrier.
// Lane role for scores: c = lane>>4 (16-elem chunk), kk = lane&15 (key).
// ---------------------------------------------------------------------------
__global__ void regions2_kernel(
    const int* __restrict__ np,
    const unsigned short* __restrict__ EinB,
    const unsigned short* __restrict__ EoutB,
    unsigned short* __restrict__ rinD, unsigned short* __restrict__ routD, int RS)
{
    __shared__ unsigned short tb_all[4][20 * 64];   // 10 KB/block
    const int wv = threadIdx.x >> 6;
    const int lane = threadIdx.x & 63;
    const int n = blockIdx.x * 4 + wv;              // 50000 = 12500*4
    unsigned short* tb = tb_all[wv];                // rows 0-9: in, 10-19: out

    const int g16 = lane >> 4, c16 = lane & 15;

    // ---- stage 20 rows, 4 rows per wide load (uint2 = 4 bf16/lane) ----
#pragma unroll
    for (int j = 0; j < 5; ++j) {
        int cr = 4 * j + g16;
        int rsel = (cr < 10) ? cr : cr - 10;
        int item = np[n * KNEAR + rsel];
        const unsigned short* src = ((cr < 10) ? EinB : EoutB)
                                    + (size_t)item * D4 + c16 * 4;
        uint2 v = *(const uint2*)src;
        *(uint2*)&tb[cr * 64 + c16 * 4] = v;
    }
    __asm__ volatile("s_waitcnt lgkmcnt(0)" ::: "memory");

    const int kk = c16;
    const int par = lane & 1, cp = lane >> 1;

#pragma unroll
    for (int pass = 0; pass < 2; ++pass) {
        const int qb = pass ? 640 : 0;    // q tile base (elements)
        const int kb = pass ? 0 : 640;    // kv tile base

        // ---- q chunk for this c-group: elements qb + c*16 .. +15 ----
        uint4 qa = *(const uint4*)&tb[qb + g16 * 16];
        uint4 qc = *(const uint4*)&tb[qb + g16 * 16 + 8];
        float qf[16];
        {
            unsigned wds[8] = {qa.x, qa.y, qa.z, qa.w, qc.x, qc.y, qc.z, qc.w};
#pragma unroll
            for (int m = 0; m < 8; ++m) {
                qf[2 * m]     = bf2f((unsigned short)(wds[m] & 0xffff));
                qf[2 * m + 1] = bf2f((unsigned short)(wds[m] >> 16));
            }
        }

        // ---- partial score: p(c,kk) = sum_i q[c*16+i]*kvflat[(c*16+i)*10+kk]
        const unsigned short* kvp = &tb[kb + g16 * 160 + kk];
        float p = 0.f;
#pragma unroll
        for (int i = 0; i < 16; ++i)
            p = fmaf(bf2f(kvp[10 * i]), qf[i], p);
        // finish reduction across the 4 c-groups
        p += __shfl_xor(p, 16);
        p += __shfl_xor(p, 32);
        float sc = p * 0.125f;            // / sqrt(64)

        // ---- softmax over kk within each 16-lane group (DPP, VALU-only) ----
        float mv = (kk < 10) ? sc : -1e30f;
        mv = fmaxf(mv, dppf<DPP_XOR1>(mv));
        mv = fmaxf(mv, dppf<DPP_XOR2>(mv));
        mv = fmaxf(mv, dppf<DPP_HMIR>(mv));
        mv = fmaxf(mv, dppf<DPP_MIR>(mv));
        float e = (kk < 10) ? __expf(sc - mv) : 0.f;
        float s = e;
        s += dppf<DPP_XOR1>(s);
        s += dppf<DPP_XOR2>(s);
        s += dppf<DPP_HMIR>(s);
        s += dppf<DPP_MIR>(s);
        float w = e / s;                  // valid in lane kk (kk<10)

        // ---- weighted sum: o[d] = sum_kk w[kk]*kv[kk][d] ----
        // lane pair (2cp, 2cp+1) covers cols 2cp..2cp+1; parity = row parity
        float oc0 = 0.f, oc1 = 0.f;
#pragma unroll
        for (int t = 0; t < 5; ++t) {
            float we = __uint_as_float(__builtin_amdgcn_readlane(__float_as_uint(w), 2 * t));
            float wo = __uint_as_float(__builtin_amdgcn_readlane(__float_as_uint(w), 2 * t + 1));
            float ws = par ? wo : we;
            unsigned v = *(const unsigned*)&tb[kb + (2 * t + par) * 64 + cp * 2];
            oc0 = fmaf(bf2f((unsigned short)(v & 0xffff)), ws, oc0);
            oc1 = fmaf(bf2f((unsigned short)(v >> 16)), ws, oc1);
        }
        oc0 += dppf<DPP_XOR1>(oc0);       // combine row parities (lane ^ 1)
        oc1 += dppf<DPP_XOR1>(oc1);
        if (!par) {
            unsigned short* dst = pass ? rinD : routD;
            *(unsigned*)&dst[(size_t)n * RS + cp * 2] = pack2(oc0, oc1);
        }
    }
}

// ---------------------------------------------------------------------------
// regions fallback (f32 tables) — round-2-proven shuffle version.
// ---------------------------------------------------------------------------
__global__ __launch_bounds__(256) void regions_fallback(
    const int* __restrict__ np,
    const float* __restrict__ EinF, const float* __restrict__ EoutF,
    unsigned short* __restrict__ rinD, unsigned short* __restrict__ routD, int RS)
{
    __shared__ float sIn[4][KNEAR * D4];
    __shared__ float sOut[4][KNEAR * D4];
    const int wave = threadIdx.x >> 6;
    const int lane = threadIdx.x & 63;
    const int n = blockIdx.x * 4 + wave;

    float* inL = sIn[wave];
    float* outL = sOut[wave];

#pragma unroll
    for (int r = 0; r < KNEAR; ++r) {
        int row = np[n * KNEAR + r];
        inL[r * D4 + lane] = EinF[(size_t)row * D4 + lane];
        outL[r * D4 + lane] = EoutF[(size_t)row * D4 + lane];
    }
    __syncthreads();

#pragma unroll
    for (int pass = 0; pass < 2; ++pass) {
        const float* kv = (pass == 0) ? outL : inL;
        const float* qs = (pass == 0) ? inL : outL;
        float q = qs[lane];
        float sc[KNEAR];
#pragma unroll
        for (int kq = 0; kq < KNEAR; ++kq) {
            float p = q * kv[lane * KNEAR + kq];
#pragma unroll
            for (int off = 1; off < 64; off <<= 1) p += __shfl_xor(p, off);
            sc[kq] = p * 0.125f;
        }
        float m = sc[0];
#pragma unroll
        for (int kq = 1; kq < KNEAR; ++kq) m = fmaxf(m, sc[kq]);
        float s = 0.f;
#pragma unroll
        for (int kq = 0; kq < KNEAR; ++kq) { sc[kq] = expf(sc[kq] - m); s += sc[kq]; }
        float inv = 1.f / s;
        float acc = 0.f;
#pragma unroll
        for (int kq = 0; kq < KNEAR; ++kq) acc += sc[kq] * kv[kq * D4 + lane];
        unsigned short* dst = (pass == 0) ? routD : rinD;
        dst[(size_t)n * RS + lane] = f2bf(acc * inv);
    }
}

// ---------------------------------------------------------------------------
// score: one block (4 waves) per batch element (round-3-proven).
// ---------------------------------------------------------------------------
template<bool FUSED>
__global__ __launch_bounds__(256, 4) void score_kernel(
    const int* __restrict__ history, const int* __restrict__ target,
    const unsigned short* __restrict__ histT,
    const float* __restrict__ E_hist,
    const unsigned short* __restrict__ rinP, const unsigned short* __restrict__ routP,
    int RS,
    const float* __restrict__ E_targ,
    const unsigned short* __restrict__ W1s,
    const float* __restrict__ b1, const float* __restrict__ W2,
    float* __restrict__ out)
{
    __shared__ __align__(16) unsigned short Xs[64][XSTRIDE];   // 33.8 KB
    __shared__ float scoreP[4][64];
    __shared__ float rowsumS[64];

    const int t = threadIdx.x;
    const int lane = t & 63;
    const int wv = t >> 6;
    const int b = blockIdx.x;
    const int ti = target[b];

    // ---- build X = hist ⊙ targ (bf16) ----
    if (FUSED) {
        const int c4 = lane * 4;               // 4 columns per thread
        float tg0, tg1, tg2, tg3;
        if (c4 < 128) {
            float4 v = *(const float4*)&E_targ[(size_t)ti * 128 + c4];
            tg0 = v.x; tg1 = v.y; tg2 = v.z; tg3 = v.w;
        } else if (c4 < 192) {
            uint2 u = *(const uint2*)&routP[(size_t)ti * RS + (c4 - 128)];
            tg0 = bf2f((unsigned short)(u.x & 0xffff)); tg1 = bf2f((unsigned short)(u.x >> 16));
            tg2 = bf2f((unsigned short)(u.y & 0xffff)); tg3 = bf2f((unsigned short)(u.y >> 16));
        } else {
            uint2 u = *(const uint2*)&rinP[(size_t)ti * RS + (c4 - 192)];
            tg0 = bf2f((unsigned short)(u.x & 0xffff)); tg1 = bf2f((unsigned short)(u.x >> 16));
            tg2 = bf2f((unsigned short)(u.y & 0xffff)); tg3 = bf2f((unsigned short)(u.y >> 16));
        }
#pragma unroll 4
        for (int h = wv; h < HISTN; h += 4) {
            int item = history[b * HISTN + h];
            uint2 u = *(const uint2*)&histT[(size_t)item * 256 + c4];
            uint2 w;
            w.x = pack2(bf2f((unsigned short)(u.x & 0xffff)) * tg0,
                        bf2f((unsigned short)(u.x >> 16)) * tg1);
            w.y = pack2(bf2f((unsigned short)(u.y & 0xffff)) * tg2,
                        bf2f((unsigned short)(u.y >> 16)) * tg3);
            *(uint2*)&Xs[h][c4] = w;
        }
    } else {
        float tg;
        if (t < 128)       tg = E_targ[(size_t)ti * 128 + t];
        else if (t < 192)  tg = bf2f(routP[(size_t)ti * RS + (t - 128)]);
        else               tg = bf2f(rinP[(size_t)ti * RS + (t - 192)]);
#pragma unroll 10
        for (int h = 0; h < HISTN; ++h) {
            int item = history[b * HISTN + h];
            float hv;
            if (t < 128)       hv = E_hist[(size_t)item * 128 + t];
            else if (t < 192)  hv = bf2f(rinP[(size_t)item * RS + (t - 128)]);
            else               hv = bf2f(routP[(size_t)item * RS + (t - 192)]);
            Xs[h][t] = f2bf(hv * tg);
        }
    }
    __syncthreads();

    // ---- GEMM: H1 = X @ W1^T; rowsum via B=ones MFMA ----
    floatx4 acc[4][2];
    floatx4 accr = (floatx4){0.f, 0.f, 0.f, 0.f};
#pragma unroll
    for (int m = 0; m < 4; ++m)
#pragma unroll
        for (int n = 0; n < 2; ++n) acc[m][n] = (floatx4){0.f, 0.f, 0.f, 0.f};

    const int nt0 = wv * 2;
    const int ar = lane & 15;
    const int kl = (lane >> 4) << 3;
    const short8v* W1f = (const short8v*)W1s;
    const short ONE = (short)0x3F80;   // bf16 1.0
    const short8v ones = {ONE, ONE, ONE, ONE, ONE, ONE, ONE, ONE};

#pragma unroll
    for (int k = 0; k < 8; ++k) {
        short8v a0 = *(const short8v*)&Xs[ar][k * 32 + kl];
        short8v a1 = *(const short8v*)&Xs[16 + ar][k * 32 + kl];
        short8v a2 = *(const short8v*)&Xs[32 + ar][k * 32 + kl];
        short8v a3 = *(const short8v*)&Xs[48 + ar][k * 32 + kl];
        short8v ax = *(const short8v*)&Xs[wv * 16 + ar][k * 32 + kl];
        short8v bf0 = W1f[(k * 8 + nt0) * 64 + lane];
        short8v bf1 = W1f[(k * 8 + nt0 + 1) * 64 + lane];
        acc[0][0] = __builtin_amdgcn_mfma_f32_16x16x32_bf16(a0, bf0, acc[0][0], 0, 0, 0);
        acc[0][1] = __builtin_amdgcn_mfma_f32_16x16x32_bf16(a0, bf1, acc[0][1], 0, 0, 0);
        acc[1][0] = __builtin_amdgcn_mfma_f32_16x16x32_bf16(a1, bf0, acc[1][0], 0, 0, 0);
        acc[1][1] = __builtin_amdgcn_mfma_f32_16x16x32_bf16(a1, bf1, acc[1][1], 0, 0, 0);
        acc[2][0] = __builtin_amdgcn_mfma_f32_16x16x32_bf16(a2, bf0, acc[2][0], 0, 0, 0);
        acc[2][1] = __builtin_amdgcn_mfma_f32_16x16x32_bf16(a2, bf1, acc[2][1], 0, 0, 0);
        acc[3][0] = __builtin_amdgcn_mfma_f32_16x16x32_bf16(a3, bf0, acc[3][0], 0, 0, 0);
        acc[3][1] = __builtin_amdgcn_mfma_f32_16x16x32_bf16(a3, bf1, acc[3][1], 0, 0, 0);
        accr      = __builtin_amdgcn_mfma_f32_16x16x32_bf16(ax, ones, accr, 0, 0, 0);
    }

    if (ar == 0) {
        int hb = wv * 16 + ((lane >> 4) << 2);
        rowsumS[hb + 0] = accr[0];
        rowsumS[hb + 1] = accr[1];
        rowsumS[hb + 2] = accr[2];
        rowsumS[hb + 3] = accr[3];
    }

    float w2v[2], b1v[2];
#pragma unroll
    for (int n = 0; n < 2; ++n) {
        int o = (nt0 + n) * 16 + ar;
        w2v[n] = W2[o];
        b1v[n] = b1[o];
    }
#pragma unroll
    for (int m = 0; m < 4; ++m) {
        float p[4] = {0.f, 0.f, 0.f, 0.f};
#pragma unroll
        for (int n = 0; n < 2; ++n)
#pragma unroll
            for (int r = 0; r < 4; ++r)
                p[r] += w2v[n] * fmaxf(acc[m][n][r] + b1v[n], 0.f);
#pragma unroll
        for (int r = 0; r < 4; ++r) {
            float v = p[r];
            v += __shfl_xor(v, 1); v += __shfl_xor(v, 2);
            v += __shfl_xor(v, 4); v += __shfl_xor(v, 8);
            if (ar == 0) scoreP[wv][m * 16 + ((lane >> 4) << 2) + r] = v;
        }
    }
    __syncthreads();

    if (wv == 0) {
        float e = 0.f, er = 0.f;
        if (lane < HISTN) {
            int item = history[b * HISTN + lane];
            float sc = scoreP[0][lane] + scoreP[1][lane] + scoreP[2][lane] + scoreP[3][lane];
            e = (item != ti) ? expf(sc) : 0.f;
            er = e * rowsumS[lane];
        }
#pragma unroll
        for (int off = 1; off < 64; off <<= 1) {
            e += __shfl_xor(e, off);
            er += __shfl_xor(er, off);
        }
        if (lane == 0) {
            float pred = er / sqrtf(e);        // denom = (sum e)^0.5
            out[b] = 1.f / (1.f + expf(-pred));
        }
    }
}

extern "C" void kernel_launch(void* const* d_in, const int* in_sizes, int n_in,
                              void* d_out, int out_size, void* d_ws, size_t ws_size,
                              hipStream_t stream) {
    const int* history = (const int*)d_in[0];        // (4096,50)
    const int* target = (const int*)d_in[1];         // (4096,)
    const int* near_pois = (const int*)d_in[2];      // (50000,10)
    // d_in[3] = target_region: unused by reference
    const float* E_in = (const float*)d_in[4];       // (50000,64)
    const float* E_out = (const float*)d_in[5];      // (50000,64)
    const float* E_hist = (const float*)d_in[6];     // (50000,128)
    const float* E_targ = (const float*)d_in[7];     // (50000,128)
    const float* W1 = (const float*)d_in[8];         // (128,256)
    const float* b1 = (const float*)d_in[9];         // (128,)
    const float* W2 = (const float*)d_in[10];        // (1,128)
    float* out = (float*)d_out;                      // (4096,)

    unsigned short* W1s = (unsigned short*)d_ws;     // 64 KB
    unsigned short* base = W1s + 32768;

    const size_t needB = 65536 + (size_t)ITEMN * 256 * 2;                 // histT
    const size_t needA = needB + 2 * (size_t)ITEMN * D4 * 2;              // + EinB/EoutB

    prep_w1<<<16, 256, 0, stream>>>(W1, W1s);

    if (ws_size >= needB) {
        unsigned short* histT = base;                     // [50000][256] bf16
        unsigned short* rinD = histT + 128;               // cols 128..191
        unsigned short* routD = histT + 192;              // cols 192..255
        cvt_bf16<128, 256><<<(ITEMN * 16 + 255) / 256, 256, 0, stream>>>(E_hist, histT);
        if (ws_size >= needA) {
            unsigned short* EinB = histT + (size_t)ITEMN * 256;
            unsigned short* EoutB = EinB + (size_t)ITEMN * D4;
            cvt_bf16<64, 64><<<(ITEMN * 8 + 255) / 256, 256, 0, stream>>>(E_in, EinB);
            cvt_bf16<64, 64><<<(ITEMN * 8 + 255) / 256, 256, 0, stream>>>(E_out, EoutB);
            regions2_kernel<<<ITEMN / 4, 256, 0, stream>>>(
                near_pois, EinB, EoutB, rinD, routD, 256);
        } else {
            regions_fallback<<<ITEMN / 4, 256, 0, stream>>>(
                near_pois, E_in, E_out, rinD, routD, 256);
        }
        score_kernel<true><<<NBATCH, 256, 0, stream>>>(
            history, target, histT, E_hist, rinD, routD, 256,
            E_targ, W1s, b1, W2, out);
    } else {
        // fallback: separate bf16 Rin/Rout, f32 E_hist
        unsigned short* Rin = base;
        unsigned short* Rout = Rin + (size_t)ITEMN * D4;
        regions_fallback<<<ITEMN / 4, 256, 0, stream>>>(
            near_pois, E_in, E_out, Rin, Rout, D4);
        score_kernel<false><<<NBATCH, 256, 0, stream>>>(
            history, target, nullptr, E_hist, Rin, Rout, D4,
            E_targ, W1s, b1, W2, out);
    }
}

// Round 5
// 93.370 us; speedup vs baseline: 5.7708x; 1.0420x over previous
//
#include <hip/hip_runtime.h>
#include <hip/hip_bf16.h>
#include <math.h>

#define EMBED 256
#define HIDDEN 128
#define NBATCH 4096
#define HISTN 50
#define KNEAR 10
#define D4 64
#define ITEMN 50000
#define XSTRIDE 264   // 256 + 8 bf16 pad -> row stride 528B (2-way conflicts = free)

typedef __attribute__((ext_vector_type(8))) short short8v;   // 8 bf16 = 4 VGPR
typedef __attribute__((ext_vector_type(4))) float floatx4;

__device__ inline float bf2f(unsigned short u) {
    return __uint_as_float(((unsigned)u) << 16);
}
__device__ inline unsigned short f2bf(float f) {
    union { __hip_bfloat16 h; unsigned short u; } cv;
    cv.h = __float2bfloat16(f);
    return cv.u;
}
__device__ inline unsigned pack2(float a, float b) {
    return (unsigned)f2bf(a) | ((unsigned)f2bf(b) << 16);
}
__device__ inline void unpack8(uint4 u, float* f) {
    f[0] = bf2f((unsigned short)(u.x & 0xffff)); f[1] = bf2f((unsigned short)(u.x >> 16));
    f[2] = bf2f((unsigned short)(u.y & 0xffff)); f[3] = bf2f((unsigned short)(u.y >> 16));
    f[4] = bf2f((unsigned short)(u.z & 0xffff)); f[5] = bf2f((unsigned short)(u.z >> 16));
    f[6] = bf2f((unsigned short)(u.w & 0xffff)); f[7] = bf2f((unsigned short)(u.w >> 16));
}

// DPP helper: combine with lane permuted by CTRL (VALU pipe, no LDS)
template<int CTRL>
__device__ __forceinline__ float dppf(float x) {
    return __uint_as_float((unsigned)__builtin_amdgcn_update_dpp(
        0, (int)__float_as_uint(x), CTRL, 0xF, 0xF, true));
}
#define DPP_XOR1 0xB1        // quad_perm [1,0,3,2]
#define DPP_XOR2 0x4E        // quad_perm [2,3,0,1]
#define DPP_HMIR 0x141       // row_half_mirror
#define DPP_MIR  0x140       // row_mirror

// ---------------------------------------------------------------------------
// prep_all: ONE kernel for all table prep (saves launch gaps).
//   [0, 800000)           : E_hist f32 -> histT bf16 (stride 256)
//   [800000, 1200000)     : E_in  -> EinB   (mode>=2)
//   [1200000, 1600000)    : E_out -> EoutB  (mode>=2)
//   tail 4096 threads     : W1 -> bf16 MFMA B-fragments (proven layout)
// ---------------------------------------------------------------------------
__global__ __launch_bounds__(256) void prep_all(
    const float* __restrict__ W1, unsigned short* __restrict__ W1s,
    const float* __restrict__ E_hist, unsigned short* __restrict__ histT,
    const float* __restrict__ E_in, unsigned short* __restrict__ EinB,
    const float* __restrict__ E_out, unsigned short* __restrict__ EoutB,
    int mode)
{
    long tid = (long)blockIdx.x * 256 + threadIdx.x;
    long off = 0;
    if (mode >= 1) {
        if (tid < (long)ITEMN * 16) {      // histT: 16 chunks of 8 per row
            int row = (int)(tid >> 4);
            int c8 = ((int)tid & 15) * 8;
            const float4* s = (const float4*)&E_hist[(size_t)row * 128 + c8];
            float4 a = s[0], b = s[1];
            uint4 o;
            o.x = pack2(a.x, a.y); o.y = pack2(a.z, a.w);
            o.z = pack2(b.x, b.y); o.w = pack2(b.z, b.w);
            *(uint4*)&histT[(size_t)row * 256 + c8] = o;
            return;
        }
        off = (long)ITEMN * 16;
        if (mode >= 2) {
            if (tid < off + (long)ITEMN * 8) {
                long i = tid - off;
                int row = (int)(i >> 3);
                int c8 = ((int)i & 7) * 8;
                const float4* s = (const float4*)&E_in[(size_t)row * 64 + c8];
                float4 a = s[0], b = s[1];
                uint4 o;
                o.x = pack2(a.x, a.y); o.y = pack2(a.z, a.w);
                o.z = pack2(b.x, b.y); o.w = pack2(b.z, b.w);
                *(uint4*)&EinB[(size_t)row * 64 + c8] = o;
                return;
            }
            off += (long)ITEMN * 8;
            if (tid < off + (long)ITEMN * 8) {
                long i = tid - off;
                int row = (int)(i >> 3);
                int c8 = ((int)i & 7) * 8;
                const float4* s = (const float4*)&E_out[(size_t)row * 64 + c8];
                float4 a = s[0], b = s[1];
                uint4 o;
                o.x = pack2(a.x, a.y); o.y = pack2(a.z, a.w);
                o.z = pack2(b.x, b.y); o.w = pack2(b.z, b.w);
                *(uint4*)&EoutB[(size_t)row * 64 + c8] = o;
                return;
            }
            off += (long)ITEMN * 8;
        }
    }
    long w = tid - off;
    if (w < 4096) {                        // W1 fragments
        int l = (int)w & 63;
        int f = (int)w >> 6;
        int k = f >> 3, nt = f & 7;
        int row = nt * 16 + (l & 15);
        int col = k * 32 + ((l >> 4) << 3);
        const float* src = W1 + row * EMBED + col;
#pragma unroll
        for (int j = 0; j < 8; ++j)
            W1s[w * 8 + j] = f2bf(src[j]);
    }
}

// ---------------------------------------------------------------------------
// regions2: one wave per item, bf16 tables, no block barrier (round-4-proven).
// ---------------------------------------------------------------------------
__global__ void regions2_kernel(
    const int* __restrict__ np,
    const unsigned short* __restrict__ EinB,
    const unsigned short* __restrict__ EoutB,
    unsigned short* __restrict__ rinD, unsigned short* __restrict__ routD, int RS)
{
    __shared__ unsigned short tb_all[4][20 * 64];   // 10 KB/block
    const int wv = threadIdx.x >> 6;
    const int lane = threadIdx.x & 63;
    const int n = blockIdx.x * 4 + wv;              // 50000 = 12500*4
    unsigned short* tb = tb_all[wv];                // rows 0-9: in, 10-19: out

    const int g16 = lane >> 4, c16 = lane & 15;

#pragma unroll
    for (int j = 0; j < 5; ++j) {
        int cr = 4 * j + g16;
        int rsel = (cr < 10) ? cr : cr - 10;
        int item = np[n * KNEAR + rsel];
        const unsigned short* src = ((cr < 10) ? EinB : EoutB)
                                    + (size_t)item * D4 + c16 * 4;
        uint2 v = *(const uint2*)src;
        *(uint2*)&tb[cr * 64 + c16 * 4] = v;
    }
    __asm__ volatile("s_waitcnt lgkmcnt(0)" ::: "memory");

    const int kk = c16;
    const int par = lane & 1, cp = lane >> 1;

#pragma unroll
    for (int pass = 0; pass < 2; ++pass) {
        const int qb = pass ? 640 : 0;    // q tile base (elements)
        const int kb = pass ? 0 : 640;    // kv tile base

        uint4 qa = *(const uint4*)&tb[qb + g16 * 16];
        uint4 qc = *(const uint4*)&tb[qb + g16 * 16 + 8];
        float qf[16];
        {
            unsigned wds[8] = {qa.x, qa.y, qa.z, qa.w, qc.x, qc.y, qc.z, qc.w};
#pragma unroll
            for (int m = 0; m < 8; ++m) {
                qf[2 * m]     = bf2f((unsigned short)(wds[m] & 0xffff));
                qf[2 * m + 1] = bf2f((unsigned short)(wds[m] >> 16));
            }
        }

        const unsigned short* kvp = &tb[kb + g16 * 160 + kk];
        float p = 0.f;
#pragma unroll
        for (int i = 0; i < 16; ++i)
            p = fmaf(bf2f(kvp[10 * i]), qf[i], p);
        p += __shfl_xor(p, 16);
        p += __shfl_xor(p, 32);
        float sc = p * 0.125f;            // / sqrt(64)

        float mv = (kk < 10) ? sc : -1e30f;
        mv = fmaxf(mv, dppf<DPP_XOR1>(mv));
        mv = fmaxf(mv, dppf<DPP_XOR2>(mv));
        mv = fmaxf(mv, dppf<DPP_HMIR>(mv));
        mv = fmaxf(mv, dppf<DPP_MIR>(mv));
        float e = (kk < 10) ? __expf(sc - mv) : 0.f;
        float s = e;
        s += dppf<DPP_XOR1>(s);
        s += dppf<DPP_XOR2>(s);
        s += dppf<DPP_HMIR>(s);
        s += dppf<DPP_MIR>(s);
        float w = e / s;

        float oc0 = 0.f, oc1 = 0.f;
#pragma unroll
        for (int t = 0; t < 5; ++t) {
            float we = __uint_as_float(__builtin_amdgcn_readlane(__float_as_uint(w), 2 * t));
            float wo = __uint_as_float(__builtin_amdgcn_readlane(__float_as_uint(w), 2 * t + 1));
            float ws = par ? wo : we;
            unsigned v = *(const unsigned*)&tb[kb + (2 * t + par) * 64 + cp * 2];
            oc0 = fmaf(bf2f((unsigned short)(v & 0xffff)), ws, oc0);
            oc1 = fmaf(bf2f((unsigned short)(v >> 16)), ws, oc1);
        }
        oc0 += dppf<DPP_XOR1>(oc0);
        oc1 += dppf<DPP_XOR1>(oc1);
        if (!par) {
            unsigned short* dst = pass ? rinD : routD;
            *(unsigned*)&dst[(size_t)n * RS + cp * 2] = pack2(oc0, oc1);
        }
    }
}

// ---------------------------------------------------------------------------
// regions fallback (f32 tables) — shuffle version (proven).
// ---------------------------------------------------------------------------
__global__ __launch_bounds__(256) void regions_fallback(
    const int* __restrict__ np,
    const float* __restrict__ EinF, const float* __restrict__ EoutF,
    unsigned short* __restrict__ rinD, unsigned short* __restrict__ routD, int RS)
{
    __shared__ float sIn[4][KNEAR * D4];
    __shared__ float sOut[4][KNEAR * D4];
    const int wave = threadIdx.x >> 6;
    const int lane = threadIdx.x & 63;
    const int n = blockIdx.x * 4 + wave;

    float* inL = sIn[wave];
    float* outL = sOut[wave];

#pragma unroll
    for (int r = 0; r < KNEAR; ++r) {
        int row = np[n * KNEAR + r];
        inL[r * D4 + lane] = EinF[(size_t)row * D4 + lane];
        outL[r * D4 + lane] = EoutF[(size_t)row * D4 + lane];
    }
    __syncthreads();

#pragma unroll
    for (int pass = 0; pass < 2; ++pass) {
        const float* kv = (pass == 0) ? outL : inL;
        const float* qs = (pass == 0) ? inL : outL;
        float q = qs[lane];
        float sc[KNEAR];
#pragma unroll
        for (int kq = 0; kq < KNEAR; ++kq) {
            float p = q * kv[lane * KNEAR + kq];
#pragma unroll
            for (int off = 1; off < 64; off <<= 1) p += __shfl_xor(p, off);
            sc[kq] = p * 0.125f;
        }
        float m = sc[0];
#pragma unroll
        for (int kq = 1; kq < KNEAR; ++kq) m = fmaxf(m, sc[kq]);
        float s = 0.f;
#pragma unroll
        for (int kq = 0; kq < KNEAR; ++kq) { sc[kq] = expf(sc[kq] - m); s += sc[kq]; }
        float inv = 1.f / s;
        float acc = 0.f;
#pragma unroll
        for (int kq = 0; kq < KNEAR; ++kq) acc += sc[kq] * kv[kq * D4 + lane];
        unsigned short* dst = (pass == 0) ? routD : rinD;
        dst[(size_t)n * RS + lane] = f2bf(acc * inv);
    }
}

// ---------------------------------------------------------------------------
// score: one block (4 waves) per batch element.
// v3: W1 fragments prefetched to VGPRs at entry; X-build with fixed 8-col
// ownership + 16B gathers + LDS-staged indices; GEMM = pure LDS + MFMA.
// ---------------------------------------------------------------------------
template<bool FUSED>
__global__ __launch_bounds__(256) void score_kernel(
    const int* __restrict__ history, const int* __restrict__ target,
    const unsigned short* __restrict__ histT,
    const float* __restrict__ E_hist,
    const unsigned short* __restrict__ rinP, const unsigned short* __restrict__ routP,
    int RS,
    const float* __restrict__ E_targ,
    const unsigned short* __restrict__ W1s,
    const float* __restrict__ b1, const float* __restrict__ W2,
    float* __restrict__ out)
{
    __shared__ __align__(16) unsigned short Xs[64][XSTRIDE];   // 33.8 KB
    __shared__ float scoreP[4][64];
    __shared__ float rowsumS[64];
    __shared__ int sidx[HISTN];

    const int t = threadIdx.x;
    const int lane = t & 63;
    const int wv = t >> 6;
    const int b = blockIdx.x;
    const int ti = target[b];
    const int nt0 = wv * 2;

    if (t < HISTN) sidx[t] = history[b * HISTN + t];

    // ---- W1 fragment prefetch (16 x b128 -> 64 VGPR, in flight during X-build)
    const short8v* W1f = (const short8v*)W1s;
    short8v w1r[16];
#pragma unroll
    for (int k = 0; k < 8; ++k) {
        w1r[k * 2]     = W1f[(k * 8 + nt0) * 64 + lane];
        w1r[k * 2 + 1] = W1f[(k * 8 + nt0 + 1) * 64 + lane];
    }

    // ---- build X = hist ⊙ targ (bf16) ----
    if (FUSED) {
        const int lane32 = lane & 31;
        const int hw = lane >> 5;
        const int c8 = lane32 * 8;          // my 8 columns, fixed
        float tg[8];
        if (c8 < 128) {
            float4 v0 = *(const float4*)&E_targ[(size_t)ti * 128 + c8];
            float4 v1 = *(const float4*)&E_targ[(size_t)ti * 128 + c8 + 4];
            tg[0] = v0.x; tg[1] = v0.y; tg[2] = v0.z; tg[3] = v0.w;
            tg[4] = v1.x; tg[5] = v1.y; tg[6] = v1.z; tg[7] = v1.w;
        } else if (c8 < 192) {
            uint4 u = *(const uint4*)&routP[(size_t)ti * RS + (c8 - 128)];
            unpack8(u, tg);
        } else {
            uint4 u = *(const uint4*)&rinP[(size_t)ti * RS + (c8 - 192)];
            unpack8(u, tg);
        }
        __syncthreads();                    // sidx visible

        int rows_[7], items_[7];
#pragma unroll
        for (int j = 0; j < 7; ++j) {
            int row = j * 8 + wv * 2 + hw;
            rows_[j] = row;
            items_[j] = sidx[row < HISTN ? row : 0];
        }
#pragma unroll
        for (int j = 0; j < 7; ++j) {
            if (rows_[j] < HISTN) {
                uint4 u = *(const uint4*)&histT[(size_t)items_[j] * 256 + c8];
                float hf[8];
                unpack8(u, hf);
                uint4 w;
                w.x = pack2(hf[0] * tg[0], hf[1] * tg[1]);
                w.y = pack2(hf[2] * tg[2], hf[3] * tg[3]);
                w.z = pack2(hf[4] * tg[4], hf[5] * tg[5]);
                w.w = pack2(hf[6] * tg[6], hf[7] * tg[7]);
                *(uint4*)&Xs[rows_[j]][c8] = w;
            }
        }
    } else {
        float tg;
        if (t < 128)       tg = E_targ[(size_t)ti * 128 + t];
        else if (t < 192)  tg = bf2f(routP[(size_t)ti * RS + (t - 128)]);
        else               tg = bf2f(rinP[(size_t)ti * RS + (t - 192)]);
#pragma unroll 10
        for (int h = 0; h < HISTN; ++h) {
            int item = history[b * HISTN + h];
            float hv;
            if (t < 128)       hv = E_hist[(size_t)item * 128 + t];
            else if (t < 192)  hv = bf2f(rinP[(size_t)item * RS + (t - 128)]);
            else               hv = bf2f(routP[(size_t)item * RS + (t - 192)]);
            Xs[h][t] = f2bf(hv * tg);
        }
    }
    __syncthreads();

    // ---- GEMM: H1 = X @ W1^T; rowsum via B=ones MFMA (B from registers) ----
    floatx4 acc[4][2];
    floatx4 accr = (floatx4){0.f, 0.f, 0.f, 0.f};
#pragma unroll
    for (int m = 0; m < 4; ++m)
#pragma unroll
        for (int n = 0; n < 2; ++n) acc[m][n] = (floatx4){0.f, 0.f, 0.f, 0.f};

    const int ar = lane & 15;
    const int kl = (lane >> 4) << 3;
    const short ONE = (short)0x3F80;   // bf16 1.0
    const short8v ones = {ONE, ONE, ONE, ONE, ONE, ONE, ONE, ONE};

#pragma unroll
    for (int k = 0; k < 8; ++k) {
        short8v a0 = *(const short8v*)&Xs[ar][k * 32 + kl];
        short8v a1 = *(const short8v*)&Xs[16 + ar][k * 32 + kl];
        short8v a2 = *(const short8v*)&Xs[32 + ar][k * 32 + kl];
        short8v a3 = *(const short8v*)&Xs[48 + ar][k * 32 + kl];
        short8v ax = *(const short8v*)&Xs[wv * 16 + ar][k * 32 + kl];
        short8v bf0 = w1r[k * 2];
        short8v bf1 = w1r[k * 2 + 1];
        acc[0][0] = __builtin_amdgcn_mfma_f32_16x16x32_bf16(a0, bf0, acc[0][0], 0, 0, 0);
        acc[0][1] = __builtin_amdgcn_mfma_f32_16x16x32_bf16(a0, bf1, acc[0][1], 0, 0, 0);
        acc[1][0] = __builtin_amdgcn_mfma_f32_16x16x32_bf16(a1, bf0, acc[1][0], 0, 0, 0);
        acc[1][1] = __builtin_amdgcn_mfma_f32_16x16x32_bf16(a1, bf1, acc[1][1], 0, 0, 0);
        acc[2][0] = __builtin_amdgcn_mfma_f32_16x16x32_bf16(a2, bf0, acc[2][0], 0, 0, 0);
        acc[2][1] = __builtin_amdgcn_mfma_f32_16x16x32_bf16(a2, bf1, acc[2][1], 0, 0, 0);
        acc[3][0] = __builtin_amdgcn_mfma_f32_16x16x32_bf16(a3, bf0, acc[3][0], 0, 0, 0);
        acc[3][1] = __builtin_amdgcn_mfma_f32_16x16x32_bf16(a3, bf1, acc[3][1], 0, 0, 0);
        accr      = __builtin_amdgcn_mfma_f32_16x16x32_bf16(ax, ones, accr, 0, 0, 0);
    }

    if (ar == 0) {
        int hb = wv * 16 + ((lane >> 4) << 2);
        rowsumS[hb + 0] = accr[0];
        rowsumS[hb + 1] = accr[1];
        rowsumS[hb + 2] = accr[2];
        rowsumS[hb + 3] = accr[3];
    }

    // ---- epilogue: partial score over this wave's 32 outputs ----
    float w2v[2], b1v[2];
#pragma unroll
    for (int n = 0; n < 2; ++n) {
        int o = (nt0 + n) * 16 + ar;
        w2v[n] = W2[o];
        b1v[n] = b1[o];
    }
#pragma unroll
    for (int m = 0; m < 4; ++m) {
        float p[4] = {0.f, 0.f, 0.f, 0.f};
#pragma unroll
        for (int n = 0; n < 2; ++n)
#pragma unroll
            for (int r = 0; r < 4; ++r)
                p[r] += w2v[n] * fmaxf(acc[m][n][r] + b1v[n], 0.f);
#pragma unroll
        for (int r = 0; r < 4; ++r) {
            float v = p[r];
            v += __shfl_xor(v, 1); v += __shfl_xor(v, 2);
            v += __shfl_xor(v, 4); v += __shfl_xor(v, 8);
            if (ar == 0) scoreP[wv][m * 16 + ((lane >> 4) << 2) + r] = v;
        }
    }
    __syncthreads();

    // ---- final: masked exp weighting, pred, sigmoid ----
    if (wv == 0) {
        float e = 0.f, er = 0.f;
        if (lane < HISTN) {
            int item = sidx[lane];
            float sc = scoreP[0][lane] + scoreP[1][lane] + scoreP[2][lane] + scoreP[3][lane];
            e = (item != ti) ? expf(sc) : 0.f;
            er = e * rowsumS[lane];
        }
#pragma unroll
        for (int off = 1; off < 64; off <<= 1) {
            e += __shfl_xor(e, off);
            er += __shfl_xor(er, off);
        }
        if (lane == 0) {
            float pred = er / sqrtf(e);        // denom = (sum e)^0.5
            out[b] = 1.f / (1.f + expf(-pred));
        }
    }
}

extern "C" void kernel_launch(void* const* d_in, const int* in_sizes, int n_in,
                              void* d_out, int out_size, void* d_ws, size_t ws_size,
                              hipStream_t stream) {
    const int* history = (const int*)d_in[0];        // (4096,50)
    const int* target = (const int*)d_in[1];         // (4096,)
    const int* near_pois = (const int*)d_in[2];      // (50000,10)
    // d_in[3] = target_region: unused by reference
    const float* E_in = (const float*)d_in[4];       // (50000,64)
    const float* E_out = (const float*)d_in[5];      // (50000,64)
    const float* E_hist = (const float*)d_in[6];     // (50000,128)
    const float* E_targ = (const float*)d_in[7];     // (50000,128)
    const float* W1 = (const float*)d_in[8];         // (128,256)
    const float* b1 = (const float*)d_in[9];         // (128,)
    const float* W2 = (const float*)d_in[10];        // (1,128)
    float* out = (float*)d_out;                      // (4096,)

    unsigned short* W1s = (unsigned short*)d_ws;     // 64 KB
    unsigned short* base = W1s + 32768;

    const size_t needB = 65536 + (size_t)ITEMN * 256 * 2;                 // histT
    const size_t needA = needB + 2 * (size_t)ITEMN * D4 * 2;              // + EinB/EoutB

    if (ws_size >= needB) {
        unsigned short* histT = base;                     // [50000][256] bf16
        unsigned short* rinD = histT + 128;               // cols 128..191
        unsigned short* routD = histT + 192;              // cols 192..255
        if (ws_size >= needA) {
            unsigned short* EinB = histT + (size_t)ITEMN * 256;
            unsigned short* EoutB = EinB + (size_t)ITEMN * D4;
            long total = (long)ITEMN * 16 + 2L * ITEMN * 8 + 4096;
            prep_all<<<(int)((total + 255) / 256), 256, 0, stream>>>(
                W1, W1s, E_hist, histT, E_in, EinB, E_out, EoutB, 2);
            regions2_kernel<<<ITEMN / 4, 256, 0, stream>>>(
                near_pois, EinB, EoutB, rinD, routD, 256);
        } else {
            long total = (long)ITEMN * 16 + 4096;
            prep_all<<<(int)((total + 255) / 256), 256, 0, stream>>>(
                W1, W1s, E_hist, histT, nullptr, nullptr, nullptr, nullptr, 1);
            regions_fallback<<<ITEMN / 4, 256, 0, stream>>>(
                near_pois, E_in, E_out, rinD, routD, 256);
        }
        score_kernel<true><<<NBATCH, 256, 0, stream>>>(
            history, target, histT, E_hist, rinD, routD, 256,
            E_targ, W1s, b1, W2, out);
    } else {
        // fallback: separate bf16 Rin/Rout, f32 E_hist
        unsigned short* Rin = base;
        unsigned short* Rout = Rin + (size_t)ITEMN * D4;
        prep_all<<<(4096 + 255) / 256, 256, 0, stream>>>(
            W1, W1s, nullptr, nullptr, nullptr, nullptr, nullptr, nullptr, 0);
        regions_fallback<<<ITEMN / 4, 256, 0, stream>>>(
            near_pois, E_in, E_out, Rin, Rout, D4);
        score_kernel<false><<<NBATCH, 256, 0, stream>>>(
            history, target, nullptr, E_hist, Rin, Rout, D4,
            E_targ, W1s, b1, W2, out);
    }
}

// Round 6
// 74.613 us; speedup vs baseline: 7.2216x; 1.2514x over previous
//
#include <hip/hip_runtime.h>
#include <hip/hip_bf16.h>
#include <math.h>

#define EMBED 256
#define HIDDEN 128
#define NBATCH 4096
#define HISTN 50
#define KNEAR 10
#define D4 64
#define ITEMN 50000
#define XSB 272            // Xs row stride in bytes (256 + 16 pad)

// fp8 scaling: histT holds 64*val, W1s holds 32*W1, Xs holds 1024*X.
// acc = 1024*32 * h1 = 32768*h1 ; accr = 1024*rowsum.
#define SH 64.0f
#define SW 32.0f
#define INV_SXSW (1.0f / 32768.0f)
#define INV_SX (1.0f / 1024.0f)

typedef __attribute__((ext_vector_type(4))) float floatx4;
typedef __attribute__((ext_vector_type(2))) float floatx2;

__device__ inline unsigned short f2bf(float f) {
    union { __hip_bfloat16 h; unsigned short u; } cv;
    cv.h = __float2bfloat16(f);
    return cv.u;
}
__device__ inline float bf2f(unsigned short u) {
    return __uint_as_float(((unsigned)u) << 16);
}
__device__ inline unsigned pack2(float a, float b) {
    return (unsigned)f2bf(a) | ((unsigned)f2bf(b) << 16);
}
// pack 4 f32 -> 4 fp8 e4m3 (bytes [a,b,c,d], saturating)
__device__ inline unsigned pk_fp8x4(float a, float b, float c, float d) {
    int v = __builtin_amdgcn_cvt_pk_fp8_f32(a, b, 0, false);
    v = __builtin_amdgcn_cvt_pk_fp8_f32(c, d, v, true);
    return (unsigned)v;
}
// unpack 4 fp8 -> 4 f32
__device__ inline void up_fp8x4(unsigned u, float* f) {
    floatx2 lo = __builtin_amdgcn_cvt_pk_f32_fp8((int)u, false);
    floatx2 hi = __builtin_amdgcn_cvt_pk_f32_fp8((int)u, true);
    f[0] = lo.x; f[1] = lo.y; f[2] = hi.x; f[3] = hi.y;
}

// DPP helper: combine with lane permuted by CTRL (VALU pipe, no LDS)
template<int CTRL>
__device__ __forceinline__ float dppf(float x) {
    return __uint_as_float((unsigned)__builtin_amdgcn_update_dpp(
        0, (int)__float_as_uint(x), CTRL, 0xF, 0xF, true));
}
#define DPP_XOR1 0xB1        // quad_perm [1,0,3,2]
#define DPP_XOR2 0x4E        // quad_perm [2,3,0,1]
#define DPP_HMIR 0x141       // row_half_mirror
#define DPP_MIR  0x140       // row_mirror

// ---------------------------------------------------------------------------
// fuse1: ONE kernel.
//   blocks [0, 12500)   : regions attention (4 items/block, one wave each),
//                         reads E_in/E_out f32, writes fp8 region cols of histT
//   blocks [12500, ...) : E_hist f32 -> histT fp8 cols 0..127 (x64 scale)
//                         + W1 -> fp8 MFMA B-fragments (x32 scale)
// The two halves write disjoint bytes of histT; prep is BW-bound, regions is
// gather-latency-bound -> good overlap within one dispatch.
// ---------------------------------------------------------------------------
__global__ __launch_bounds__(256) void fuse1(
    const int* __restrict__ np,
    const float* __restrict__ E_in, const float* __restrict__ E_out,
    const float* __restrict__ E_hist, const float* __restrict__ W1,
    unsigned char* __restrict__ histT, unsigned char* __restrict__ W1s)
{
    __shared__ unsigned short tb_all[4][20 * 64];   // 10 KB (regions only)

    if (blockIdx.x < ITEMN / 4) {
        const int wv = threadIdx.x >> 6;
        const int lane = threadIdx.x & 63;
        const int n = blockIdx.x * 4 + wv;          // 50000 = 12500*4
        unsigned short* tb = tb_all[wv];            // rows 0-9: in, 10-19: out

        const int g16 = lane >> 4, c16 = lane & 15;

        // stage 20 rows (f32 source -> bf16 LDS), 4 rows per iteration
#pragma unroll
        for (int j = 0; j < 5; ++j) {
            int cr = 4 * j + g16;
            int rsel = (cr < 10) ? cr : cr - 10;
            int item = np[n * KNEAR + rsel];
            const float* srcf = ((cr < 10) ? E_in : E_out)
                                + (size_t)item * D4 + c16 * 4;
            float4 v = *(const float4*)srcf;
            uint2 w;
            w.x = pack2(v.x, v.y);
            w.y = pack2(v.z, v.w);
            *(uint2*)&tb[cr * 64 + c16 * 4] = w;
        }
        __asm__ volatile("s_waitcnt lgkmcnt(0)" ::: "memory");

        const int kk = c16;
        const int par = lane & 1, cp = lane >> 1;

#pragma unroll
        for (int pass = 0; pass < 2; ++pass) {
            const int qb = pass ? 640 : 0;    // q tile base (elements)
            const int kb = pass ? 0 : 640;    // kv tile base

            uint4 qa = *(const uint4*)&tb[qb + g16 * 16];
            uint4 qc = *(const uint4*)&tb[qb + g16 * 16 + 8];
            float qf[16];
            {
                unsigned wds[8] = {qa.x, qa.y, qa.z, qa.w, qc.x, qc.y, qc.z, qc.w};
#pragma unroll
                for (int m = 0; m < 8; ++m) {
                    qf[2 * m]     = bf2f((unsigned short)(wds[m] & 0xffff));
                    qf[2 * m + 1] = bf2f((unsigned short)(wds[m] >> 16));
                }
            }

            // scores[kk] = sum_d q[d]*kvflat[d*10+kk]   (reshape trick)
            const unsigned short* kvp = &tb[kb + g16 * 160 + kk];
            float p = 0.f;
#pragma unroll
            for (int i = 0; i < 16; ++i)
                p = fmaf(bf2f(kvp[10 * i]), qf[i], p);
            p += __shfl_xor(p, 16);
            p += __shfl_xor(p, 32);
            float sc = p * 0.125f;            // / sqrt(64)

            // softmax over 10 keys within each 16-lane group (DPP, VALU-only)
            float mv = (kk < 10) ? sc : -1e30f;
            mv = fmaxf(mv, dppf<DPP_XOR1>(mv));
            mv = fmaxf(mv, dppf<DPP_XOR2>(mv));
            mv = fmaxf(mv, dppf<DPP_HMIR>(mv));
            mv = fmaxf(mv, dppf<DPP_MIR>(mv));
            float e = (kk < 10) ? __expf(sc - mv) : 0.f;
            float s = e;
            s += dppf<DPP_XOR1>(s);
            s += dppf<DPP_XOR2>(s);
            s += dppf<DPP_HMIR>(s);
            s += dppf<DPP_MIR>(s);
            float w = e / s;

            // weighted sum over keys; lane pair covers 2 output dims
            float oc0 = 0.f, oc1 = 0.f;
#pragma unroll
            for (int q = 0; q < 5; ++q) {
                float we = __uint_as_float(__builtin_amdgcn_readlane(__float_as_uint(w), 2 * q));
                float wo = __uint_as_float(__builtin_amdgcn_readlane(__float_as_uint(w), 2 * q + 1));
                float ws = par ? wo : we;
                unsigned v = *(const unsigned*)&tb[kb + (2 * q + par) * 64 + cp * 2];
                oc0 = fmaf(bf2f((unsigned short)(v & 0xffff)), ws, oc0);
                oc1 = fmaf(bf2f((unsigned short)(v >> 16)), ws, oc1);
            }
            oc0 += dppf<DPP_XOR1>(oc0);       // combine row parities
            oc1 += dppf<DPP_XOR1>(oc1);
            if (!par) {
                // pass0 -> region_out -> histT cols 192.. ; pass1 -> Rin -> 128..
                unsigned char* dst = histT + (size_t)n * 256
                                     + (pass ? 128 : 192) + cp * 2;
                int v2 = __builtin_amdgcn_cvt_pk_fp8_f32(oc0 * SH, oc1 * SH, 0, false);
                *(unsigned short*)dst = (unsigned short)(v2 & 0xffff);
            }
        }
        return;
    }

    // ---- prep part ----
    long t = (long)(blockIdx.x - ITEMN / 4) * 256 + threadIdx.x;
    if (t < (long)ITEMN * 16) {               // histT hist cols (fp8, x64)
        int row = (int)(t >> 4);
        int c8 = ((int)t & 15) * 8;
        const float4* s = (const float4*)&E_hist[(size_t)row * 128 + c8];
        float4 a = s[0], b = s[1];
        uint2 o;
        o.x = pk_fp8x4(a.x * SH, a.y * SH, a.z * SH, a.w * SH);
        o.y = pk_fp8x4(b.x * SH, b.y * SH, b.z * SH, b.w * SH);
        *(uint2*)&histT[(size_t)row * 256 + c8] = o;
        return;
    }
    t -= (long)ITEMN * 16;
    if (t < 4096) {                           // W1 -> fp8 B-fragments (x32)
        int l = (int)t & 63;
        int f = (int)t >> 6;
        int k = f >> 3, nt = f & 7;
        int row = nt * 16 + (l & 15);
        int col = k * 32 + ((l >> 4) << 3);
        const float* src = W1 + row * EMBED + col;
        uint2 o;
        o.x = pk_fp8x4(src[0] * SW, src[1] * SW, src[2] * SW, src[3] * SW);
        o.y = pk_fp8x4(src[4] * SW, src[5] * SW, src[6] * SW, src[7] * SW);
        *(uint2*)&W1s[(size_t)t * 8] = o;
    }
}

// ---------------------------------------------------------------------------
// score: one block (4 waves) per batch element. fp8 X (LDS) and fp8 W1,
// mfma_f32_16x16x32_fp8_fp8; r4-proven X-build shape (13 x 4B gathers/thread,
// uniform s_load indices); f32 epilogue with descaling.
// ---------------------------------------------------------------------------
__global__ __launch_bounds__(256, 6) void score_kernel(
    const int* __restrict__ history, const int* __restrict__ target,
    const unsigned char* __restrict__ histT,
    const float* __restrict__ E_targ,
    const unsigned char* __restrict__ W1s,
    const float* __restrict__ b1, const float* __restrict__ W2,
    float* __restrict__ out)
{
    __shared__ __align__(16) unsigned char Xs[64][XSB];   // 17.4 KB
    __shared__ float scoreP[4][64];
    __shared__ float rowsumS[64];

    const int t = threadIdx.x;
    const int lane = t & 63;
    const int wv = t >> 6;
    const int b = blockIdx.x;
    const int ti = target[b];
    const int nt0 = wv * 2;
    const int c4 = lane * 4;

    // tg factors for my 4 columns, pre-multiplied so Xs = 1024*X:
    //   hist_fp8 = 64*hist -> Xs = hist_fp8 * (tg*16)
    float tgs[4];
    if (c4 < 128) {
        float4 v = *(const float4*)&E_targ[(size_t)ti * 128 + c4];
        tgs[0] = v.x * 16.f; tgs[1] = v.y * 16.f;
        tgs[2] = v.z * 16.f; tgs[3] = v.w * 16.f;
    } else {
        // targ = [E_targ | Rout | Rin]; histT = [E_hist | Rin | Rout]
        int src = (c4 < 192) ? (c4 + 64) : (c4 - 64);
        unsigned u = *(const unsigned*)&histT[(size_t)ti * 256 + src];
        float f[4]; up_fp8x4(u, f);                 // = 64*tg
        tgs[0] = f[0] * 0.25f; tgs[1] = f[1] * 0.25f;
        tgs[2] = f[2] * 0.25f; tgs[3] = f[3] * 0.25f;
    }

    // ---- build X (fp8, scaled by 1024) ----
#pragma unroll 4
    for (int h = wv; h < HISTN; h += 4) {
        int item = history[b * HISTN + h];          // uniform -> s_load
        unsigned u = *(const unsigned*)&histT[(size_t)item * 256 + c4];
        float f[4]; up_fp8x4(u, f);
        *(unsigned*)&Xs[h][c4] =
            pk_fp8x4(f[0] * tgs[0], f[1] * tgs[1], f[2] * tgs[2], f[3] * tgs[3]);
    }
    // rows 50..63 left uninitialized: row i of D depends only on row i of A.
    __syncthreads();

    // ---- GEMM: H1 = X @ W1^T (fp8 MFMA); rowsum via B=ones ----
    floatx4 acc[4][2];
    floatx4 accr = (floatx4){0.f, 0.f, 0.f, 0.f};
#pragma unroll
    for (int m = 0; m < 4; ++m)
#pragma unroll
        for (int n = 0; n < 2; ++n) acc[m][n] = (floatx4){0.f, 0.f, 0.f, 0.f};

    const int ar = lane & 15;
    const int kb8 = (lane >> 4) << 3;               // byte offset within k-step
    const long* W1f = (const long*)W1s;
    const long ones = 0x3838383838383838L;          // fp8 e4m3 1.0 x8

#pragma unroll
    for (int k = 0; k < 8; ++k) {
        long a0 = *(const long*)&Xs[ar][k * 32 + kb8];
        long a1 = *(const long*)&Xs[16 + ar][k * 32 + kb8];
        long a2 = *(const long*)&Xs[32 + ar][k * 32 + kb8];
        long a3 = *(const long*)&Xs[48 + ar][k * 32 + kb8];
        long ax = *(const long*)&Xs[wv * 16 + ar][k * 32 + kb8];
        long bq0 = W1f[(k * 8 + nt0) * 64 + lane];
        long bq1 = W1f[(k * 8 + nt0 + 1) * 64 + lane];
        acc[0][0] = __builtin_amdgcn_mfma_f32_16x16x32_fp8_fp8(a0, bq0, acc[0][0], 0, 0, 0);
        acc[0][1] = __builtin_amdgcn_mfma_f32_16x16x32_fp8_fp8(a0, bq1, acc[0][1], 0, 0, 0);
        acc[1][0] = __builtin_amdgcn_mfma_f32_16x16x32_fp8_fp8(a1, bq0, acc[1][0], 0, 0, 0);
        acc[1][1] = __builtin_amdgcn_mfma_f32_16x16x32_fp8_fp8(a1, bq1, acc[1][1], 0, 0, 0);
        acc[2][0] = __builtin_amdgcn_mfma_f32_16x16x32_fp8_fp8(a2, bq0, acc[2][0], 0, 0, 0);
        acc[2][1] = __builtin_amdgcn_mfma_f32_16x16x32_fp8_fp8(a2, bq1, acc[2][1], 0, 0, 0);
        acc[3][0] = __builtin_amdgcn_mfma_f32_16x16x32_fp8_fp8(a3, bq0, acc[3][0], 0, 0, 0);
        acc[3][1] = __builtin_amdgcn_mfma_f32_16x16x32_fp8_fp8(a3, bq1, acc[3][1], 0, 0, 0);
        accr      = __builtin_amdgcn_mfma_f32_16x16x32_fp8_fp8(ax, ones, accr, 0, 0, 0);
    }

    // rowsum: wave wv owns rows wv*16..wv*16+15 (descale by 1/1024)
    if (ar == 0) {
        int hb = wv * 16 + ((lane >> 4) << 2);
        rowsumS[hb + 0] = accr[0] * INV_SX;
        rowsumS[hb + 1] = accr[1] * INV_SX;
        rowsumS[hb + 2] = accr[2] * INV_SX;
        rowsumS[hb + 3] = accr[3] * INV_SX;
    }

    // ---- epilogue: partial score over this wave's 32 outputs ----
    float w2v[2], b1v[2];
#pragma unroll
    for (int n = 0; n < 2; ++n) {
        int o = (nt0 + n) * 16 + ar;
        w2v[n] = W2[o];
        b1v[n] = b1[o];
    }
#pragma unroll
    for (int m = 0; m < 4; ++m) {
        float p[4] = {0.f, 0.f, 0.f, 0.f};
#pragma unroll
        for (int n = 0; n < 2; ++n)
#pragma unroll
            for (int r = 0; r < 4; ++r)
                p[r] += w2v[n] * fmaxf(acc[m][n][r] * INV_SXSW + b1v[n], 0.f);
#pragma unroll
        for (int r = 0; r < 4; ++r) {
            float v = p[r];
            v += __shfl_xor(v, 1); v += __shfl_xor(v, 2);
            v += __shfl_xor(v, 4); v += __shfl_xor(v, 8);
            if (ar == 0) scoreP[wv][m * 16 + ((lane >> 4) << 2) + r] = v;
        }
    }
    __syncthreads();

    // ---- final: masked exp weighting, pred, sigmoid ----
    if (wv == 0) {
        float e = 0.f, er = 0.f;
        if (lane < HISTN) {
            int item = history[b * HISTN + lane];
            float sc = scoreP[0][lane] + scoreP[1][lane] + scoreP[2][lane] + scoreP[3][lane];
            e = (item != ti) ? expf(sc) : 0.f;
            er = e * rowsumS[lane];
        }
#pragma unroll
        for (int off = 1; off < 64; off <<= 1) {
            e += __shfl_xor(e, off);
            er += __shfl_xor(er, off);
        }
        if (lane == 0) {
            float pred = er / sqrtf(e);        // denom = (sum e)^0.5
            out[b] = 1.f / (1.f + expf(-pred));
        }
    }
}

extern "C" void kernel_launch(void* const* d_in, const int* in_sizes, int n_in,
                              void* d_out, int out_size, void* d_ws, size_t ws_size,
                              hipStream_t stream) {
    const int* history = (const int*)d_in[0];        // (4096,50)
    const int* target = (const int*)d_in[1];         // (4096,)
    const int* near_pois = (const int*)d_in[2];      // (50000,10)
    // d_in[3] = target_region: unused by reference
    const float* E_in = (const float*)d_in[4];       // (50000,64)
    const float* E_out = (const float*)d_in[5];      // (50000,64)
    const float* E_hist = (const float*)d_in[6];     // (50000,128)
    const float* E_targ = (const float*)d_in[7];     // (50000,128)
    const float* W1 = (const float*)d_in[8];         // (128,256)
    const float* b1 = (const float*)d_in[9];         // (128,)
    const float* W2 = (const float*)d_in[10];        // (1,128)
    float* out = (float*)d_out;                      // (4096,)

    unsigned char* W1s = (unsigned char*)d_ws;               // 32 KB fp8 frags
    unsigned char* histT = W1s + 32768;                      // [50000][256B] fp8

    // grid: 12500 regions blocks + ceil((800000+4096)/256) prep blocks
    const int prepBlocks = (int)(((long)ITEMN * 16 + 4096 + 255) / 256);
    fuse1<<<ITEMN / 4 + prepBlocks, 256, 0, stream>>>(
        near_pois, E_in, E_out, E_hist, W1, histT, W1s);
    score_kernel<<<NBATCH, 256, 0, stream>>>(
        history, target, histT, E_targ, W1s, b1, W2, out);
}

// Round 7
// 69.182 us; speedup vs baseline: 7.7885x; 1.0785x over previous
//
#include <hip/hip_runtime.h>
#include <hip/hip_bf16.h>
#include <math.h>

#define EMBED 256
#define HIDDEN 128
#define NBATCH 4096
#define HISTN 50
#define KNEAR 10
#define D4 64
#define ITEMN 50000
#define XSB 272            // Xs row stride in bytes (256 + 16 pad)
#define RBLK (ITEMN / 4)   // 12500 regions blocks

// fp8 scaling: histT holds 64*val, W1s holds 32*W1, Xs holds 1024*X.
#define SH 64.0f
#define SW 32.0f
#define INV_SXSW (1.0f / 32768.0f)
#define INV_SX (1.0f / 1024.0f)

typedef __attribute__((ext_vector_type(4))) float floatx4;
typedef __attribute__((ext_vector_type(2))) float floatx2;
typedef __attribute__((ext_vector_type(2))) __fp16 half2v;

__device__ inline unsigned pkh2(float a, float b) {       // 2 f32 -> packed f16
    union { half2v h; unsigned u; } cv;
    cv.h = __builtin_amdgcn_cvt_pkrtz(a, b);
    return cv.u;
}
__device__ inline float h2f(unsigned short u) {           // f16 -> f32
    union { unsigned short u; __fp16 h; } cv; cv.u = u;
    return (float)cv.h;
}
// pack 4 f32 -> 4 fp8 e4m3
__device__ inline unsigned pk_fp8x4(float a, float b, float c, float d) {
    int v = __builtin_amdgcn_cvt_pk_fp8_f32(a, b, 0, false);
    v = __builtin_amdgcn_cvt_pk_fp8_f32(c, d, v, true);
    return (unsigned)v;
}
// unpack 4 fp8 -> 4 f32
__device__ inline void up_fp8x4(unsigned u, float* f) {
    floatx2 lo = __builtin_amdgcn_cvt_pk_f32_fp8((int)u, false);
    floatx2 hi = __builtin_amdgcn_cvt_pk_f32_fp8((int)u, true);
    f[0] = lo.x; f[1] = lo.y; f[2] = hi.x; f[3] = hi.y;
}

template<int CTRL>
__device__ __forceinline__ float dppf(float x) {
    return __uint_as_float((unsigned)__builtin_amdgcn_update_dpp(
        0, (int)__float_as_uint(x), CTRL, 0xF, 0xF, true));
}
#define DPP_XOR1 0xB1        // quad_perm [1,0,3,2]
#define DPP_XOR2 0x4E        // quad_perm [2,3,0,1]
#define DPP_HMIR 0x141       // row_half_mirror
#define DPP_MIR  0x140       // row_mirror

// ---------------------------------------------------------------------------
// prep_eio: EioT[item] = [E_in row (64 f16) | E_out row (64 f16)]  (256 B/row)
// 800000 threads, 8 elems each, fully coalesced.
// ---------------------------------------------------------------------------
__global__ __launch_bounds__(256) void prep_eio(
    const float* __restrict__ E_in, const float* __restrict__ E_out,
    unsigned short* __restrict__ EioT)
{
    int tid = blockIdx.x * 256 + threadIdx.x;      // < 800000 exactly
    int row = tid >> 4, c = tid & 15;
    const float* src = (c < 8) ? &E_in[(size_t)row * 64 + (c & 7) * 8]
                               : &E_out[(size_t)row * 64 + (c & 7) * 8];
    float4 a = ((const float4*)src)[0];
    float4 b = ((const float4*)src)[1];
    uint4 o;
    o.x = pkh2(a.x, a.y); o.y = pkh2(a.z, a.w);
    o.z = pkh2(b.x, b.y); o.w = pkh2(b.z, b.w);
    *(uint4*)&EioT[(size_t)row * 128 + c * 8] = o;
}

// ---------------------------------------------------------------------------
// regions3 (+ tail prep): blocks [0,12500): per-item attention, f16 tables,
// verbatim b128 staging, f16 math; blocks [12500,...): E_hist->histT fp8 and
// W1 -> fp8 MFMA B-fragments (BW-bound, overlaps the latency-bound blocks).
// ---------------------------------------------------------------------------
__global__ __launch_bounds__(256) void regions3(
    const int* __restrict__ np,
    const unsigned short* __restrict__ EioT,
    const float* __restrict__ E_hist, const float* __restrict__ W1,
    unsigned char* __restrict__ histT, unsigned char* __restrict__ W1s)
{
    __shared__ unsigned short tiles[4][2][KNEAR * D4];   // 10 KB; [wv][in/out]

    if (blockIdx.x < RBLK) {
        const int wv = threadIdx.x >> 6;
        const int lane = threadIdx.x & 63;
        const int n = blockIdx.x * 4 + wv;          // 50000 = 12500*4
        const int g16 = lane >> 4, c16 = lane & 15;
        const int half = c16 >> 3, col = (c16 & 7) * 8;

        // ---- stage 10 combined rows; b128 verbatim copy (no conversion) ----
#pragma unroll
        for (int j = 0; j < 3; ++j) {
            int r = j * 4 + g16;
            if (r < KNEAR) {
                int item = np[n * KNEAR + r];
                uint4 v = *(const uint4*)&EioT[(size_t)item * 128 + c16 * 8];
                *(uint4*)&tiles[wv][half][r * 64 + col] = v;
            }
        }
        __asm__ volatile("s_waitcnt lgkmcnt(0)" ::: "memory");

        const int kk = c16;
        const int par = lane & 1, cp = lane >> 1;

#pragma unroll
        for (int pass = 0; pass < 2; ++pass) {
            // pass0: q = in row0, kv = out -> region_out (histT cols 192..)
            // pass1: q = out row0, kv = in -> region_in  (histT cols 128..)
            const unsigned short* qrow = tiles[wv][pass];
            const unsigned short* kvt = tiles[wv][1 - pass];

            float qf[16];
            {
                uint4 qa = *(const uint4*)&qrow[g16 * 16];
                uint4 qb = *(const uint4*)&qrow[g16 * 16 + 8];
                unsigned wd[8] = {qa.x, qa.y, qa.z, qa.w, qb.x, qb.y, qb.z, qb.w};
#pragma unroll
                for (int m = 0; m < 8; ++m) {
                    qf[2 * m]     = h2f((unsigned short)(wd[m] & 0xffff));
                    qf[2 * m + 1] = h2f((unsigned short)(wd[m] >> 16));
                }
            }

            // scores[kk] = sum_d q[d]*kvflat[d*10+kk]   (reshape trick)
            const unsigned short* kvp = &kvt[g16 * 160 + kk];
            float p = 0.f;
#pragma unroll
            for (int i = 0; i < 16; ++i)
                p = fmaf(h2f(kvp[10 * i]), qf[i], p);
            p += __shfl_xor(p, 16);
            p += __shfl_xor(p, 32);
            float sc = p * 0.125f;            // / sqrt(64)

            // softmax over 10 keys within each 16-lane group (DPP, VALU-only)
            float mv = (kk < 10) ? sc : -1e30f;
            mv = fmaxf(mv, dppf<DPP_XOR1>(mv));
            mv = fmaxf(mv, dppf<DPP_XOR2>(mv));
            mv = fmaxf(mv, dppf<DPP_HMIR>(mv));
            mv = fmaxf(mv, dppf<DPP_MIR>(mv));
            float e = (kk < 10) ? __expf(sc - mv) : 0.f;
            float s = e;
            s += dppf<DPP_XOR1>(s);
            s += dppf<DPP_XOR2>(s);
            s += dppf<DPP_HMIR>(s);
            s += dppf<DPP_MIR>(s);
            float w = e / s;

            // weighted sum over keys; lane pair covers 2 output dims
            float oc0 = 0.f, oc1 = 0.f;
#pragma unroll
            for (int q = 0; q < 5; ++q) {
                float we = __uint_as_float(__builtin_amdgcn_readlane(__float_as_uint(w), 2 * q));
                float wo = __uint_as_float(__builtin_amdgcn_readlane(__float_as_uint(w), 2 * q + 1));
                float ws = par ? wo : we;
                unsigned v = *(const unsigned*)&kvt[(2 * q + par) * 64 + cp * 2];
                oc0 = fmaf(h2f((unsigned short)(v & 0xffff)), ws, oc0);
                oc1 = fmaf(h2f((unsigned short)(v >> 16)), ws, oc1);
            }
            oc0 += dppf<DPP_XOR1>(oc0);       // combine row parities
            oc1 += dppf<DPP_XOR1>(oc1);
            if (!par) {
                unsigned char* dst = histT + (size_t)n * 256
                                     + (pass ? 128 : 192) + cp * 2;
                int v2 = __builtin_amdgcn_cvt_pk_fp8_f32(oc0 * SH, oc1 * SH, 0, false);
                *(unsigned short*)dst = (unsigned short)(v2 & 0xffff);
            }
        }
        return;
    }

    // ---- tail prep ----
    long t = (long)(blockIdx.x - RBLK) * 256 + threadIdx.x;
    if (t < (long)ITEMN * 16) {               // histT hist cols (fp8, x64)
        int row = (int)(t >> 4);
        int c8 = ((int)t & 15) * 8;
        const float4* s = (const float4*)&E_hist[(size_t)row * 128 + c8];
        float4 a = s[0], b = s[1];
        uint2 o;
        o.x = pk_fp8x4(a.x * SH, a.y * SH, a.z * SH, a.w * SH);
        o.y = pk_fp8x4(b.x * SH, b.y * SH, b.z * SH, b.w * SH);
        *(uint2*)&histT[(size_t)row * 256 + c8] = o;
        return;
    }
    t -= (long)ITEMN * 16;
    if (t < 4096) {                           // W1 -> fp8 B-fragments (x32)
        int l = (int)t & 63;
        int f = (int)t >> 6;
        int k = f >> 3, nt = f & 7;
        int row = nt * 16 + (l & 15);
        int col = k * 32 + ((l >> 4) << 3);
        const float* src = W1 + row * EMBED + col;
        uint2 o;
        o.x = pk_fp8x4(src[0] * SW, src[1] * SW, src[2] * SW, src[3] * SW);
        o.y = pk_fp8x4(src[4] * SW, src[5] * SW, src[6] * SW, src[7] * SW);
        *(uint2*)&W1s[(size_t)t * 8] = o;
    }
}

// ---------------------------------------------------------------------------
// score: one block (4 waves) per batch element. fp8 X (LDS) + fp8 W1 MFMA.
// X-build: issue all 13 gathers first (T14), then unpack/mul/pack/write.
// ---------------------------------------------------------------------------
__global__ __launch_bounds__(256, 6) void score_kernel(
    const int* __restrict__ history, const int* __restrict__ target,
    const unsigned char* __restrict__ histT,
    const float* __restrict__ E_targ,
    const unsigned char* __restrict__ W1s,
    const float* __restrict__ b1, const float* __restrict__ W2,
    float* __restrict__ out)
{
    __shared__ __align__(16) unsigned char Xs[64][XSB];   // 17.4 KB
    __shared__ float scoreP[4][64];
    __shared__ float rowsumS[64];

    const int t = threadIdx.x;
    const int lane = t & 63;
    const int wv = t >> 6;
    const int b = blockIdx.x;
    const int ti = target[b];
    const int nt0 = wv * 2;
    const int c4 = lane * 4;

    // ---- issue all gathers up front ----
    unsigned uu[13];
    int hrow[13];
#pragma unroll
    for (int j = 0; j < 13; ++j) {
        int h = wv + j * 4;
        hrow[j] = h;
        if (h < HISTN) {
            int item = history[b * HISTN + h];
            uu[j] = *(const unsigned*)&histT[(size_t)item * 256 + c4];
        }
    }

    // tg factors for my 4 columns, pre-multiplied so Xs = 1024*X
    float tgs[4];
    if (c4 < 128) {
        float4 v = *(const float4*)&E_targ[(size_t)ti * 128 + c4];
        tgs[0] = v.x * 16.f; tgs[1] = v.y * 16.f;
        tgs[2] = v.z * 16.f; tgs[3] = v.w * 16.f;
    } else {
        // targ = [E_targ | Rout | Rin]; histT = [E_hist | Rin | Rout]
        int src = (c4 < 192) ? (c4 + 64) : (c4 - 64);
        unsigned u = *(const unsigned*)&histT[(size_t)ti * 256 + src];
        float f[4]; up_fp8x4(u, f);                 // = 64*tg
        tgs[0] = f[0] * 0.25f; tgs[1] = f[1] * 0.25f;
        tgs[2] = f[2] * 0.25f; tgs[3] = f[3] * 0.25f;
    }

    // ---- process + write X (fp8, scaled by 1024) ----
#pragma unroll
    for (int j = 0; j < 13; ++j) {
        if (hrow[j] < HISTN) {
            float f[4]; up_fp8x4(uu[j], f);
            *(unsigned*)&Xs[hrow[j]][c4] =
                pk_fp8x4(f[0] * tgs[0], f[1] * tgs[1], f[2] * tgs[2], f[3] * tgs[3]);
        }
    }
    __syncthreads();

    // ---- GEMM: H1 = X @ W1^T (fp8 MFMA); rowsum via B=ones ----
    floatx4 acc[4][2];
    floatx4 accr = (floatx4){0.f, 0.f, 0.f, 0.f};
#pragma unroll
    for (int m = 0; m < 4; ++m)
#pragma unroll
        for (int n = 0; n < 2; ++n) acc[m][n] = (floatx4){0.f, 0.f, 0.f, 0.f};

    const int ar = lane & 15;
    const int kb8 = (lane >> 4) << 3;
    const long* W1f = (const long*)W1s;
    const long ones = 0x3838383838383838L;          // fp8 e4m3 1.0 x8

#pragma unroll
    for (int k = 0; k < 8; ++k) {
        long a0 = *(const long*)&Xs[ar][k * 32 + kb8];
        long a1 = *(const long*)&Xs[16 + ar][k * 32 + kb8];
        long a2 = *(const long*)&Xs[32 + ar][k * 32 + kb8];
        long a3 = *(const long*)&Xs[48 + ar][k * 32 + kb8];
        long ax = *(const long*)&Xs[wv * 16 + ar][k * 32 + kb8];
        long bq0 = W1f[(k * 8 + nt0) * 64 + lane];
        long bq1 = W1f[(k * 8 + nt0 + 1) * 64 + lane];
        acc[0][0] = __builtin_amdgcn_mfma_f32_16x16x32_fp8_fp8(a0, bq0, acc[0][0], 0, 0, 0);
        acc[0][1] = __builtin_amdgcn_mfma_f32_16x16x32_fp8_fp8(a0, bq1, acc[0][1], 0, 0, 0);
        acc[1][0] = __builtin_amdgcn_mfma_f32_16x16x32_fp8_fp8(a1, bq0, acc[1][0], 0, 0, 0);
        acc[1][1] = __builtin_amdgcn_mfma_f32_16x16x32_fp8_fp8(a1, bq1, acc[1][1], 0, 0, 0);
        acc[2][0] = __builtin_amdgcn_mfma_f32_16x16x32_fp8_fp8(a2, bq0, acc[2][0], 0, 0, 0);
        acc[2][1] = __builtin_amdgcn_mfma_f32_16x16x32_fp8_fp8(a2, bq1, acc[2][1], 0, 0, 0);
        acc[3][0] = __builtin_amdgcn_mfma_f32_16x16x32_fp8_fp8(a3, bq0, acc[3][0], 0, 0, 0);
        acc[3][1] = __builtin_amdgcn_mfma_f32_16x16x32_fp8_fp8(a3, bq1, acc[3][1], 0, 0, 0);
        accr      = __builtin_amdgcn_mfma_f32_16x16x32_fp8_fp8(ax, ones, accr, 0, 0, 0);
    }

    if (ar == 0) {
        int hb = wv * 16 + ((lane >> 4) << 2);
        rowsumS[hb + 0] = accr[0] * INV_SX;
        rowsumS[hb + 1] = accr[1] * INV_SX;
        rowsumS[hb + 2] = accr[2] * INV_SX;
        rowsumS[hb + 3] = accr[3] * INV_SX;
    }

    float w2v[2], b1v[2];
#pragma unroll
    for (int n = 0; n < 2; ++n) {
        int o = (nt0 + n) * 16 + ar;
        w2v[n] = W2[o];
        b1v[n] = b1[o];
    }
#pragma unroll
    for (int m = 0; m < 4; ++m) {
        float p[4] = {0.f, 0.f, 0.f, 0.f};
#pragma unroll
        for (int n = 0; n < 2; ++n)
#pragma unroll
            for (int r = 0; r < 4; ++r)
                p[r] += w2v[n] * fmaxf(acc[m][n][r] * INV_SXSW + b1v[n], 0.f);
#pragma unroll
        for (int r = 0; r < 4; ++r) {
            float v = p[r];
            v += __shfl_xor(v, 1); v += __shfl_xor(v, 2);
            v += __shfl_xor(v, 4); v += __shfl_xor(v, 8);
            if (ar == 0) scoreP[wv][m * 16 + ((lane >> 4) << 2) + r] = v;
        }
    }
    __syncthreads();

    if (wv == 0) {
        float e = 0.f, er = 0.f;
        if (lane < HISTN) {
            int item = history[b * HISTN + lane];
            float sc = scoreP[0][lane] + scoreP[1][lane] + scoreP[2][lane] + scoreP[3][lane];
            e = (item != ti) ? expf(sc) : 0.f;
            er = e * rowsumS[lane];
        }
#pragma unroll
        for (int off = 1; off < 64; off <<= 1) {
            e += __shfl_xor(e, off);
            er += __shfl_xor(er, off);
        }
        if (lane == 0) {
            float pred = er / sqrtf(e);        // denom = (sum e)^0.5
            out[b] = 1.f / (1.f + expf(-pred));
        }
    }
}

extern "C" void kernel_launch(void* const* d_in, const int* in_sizes, int n_in,
                              void* d_out, int out_size, void* d_ws, size_t ws_size,
                              hipStream_t stream) {
    const int* history = (const int*)d_in[0];        // (4096,50)
    const int* target = (const int*)d_in[1];         // (4096,)
    const int* near_pois = (const int*)d_in[2];      // (50000,10)
    // d_in[3] = target_region: unused by reference
    const float* E_in = (const float*)d_in[4];       // (50000,64)
    const float* E_out = (const float*)d_in[5];      // (50000,64)
    const float* E_hist = (const float*)d_in[6];     // (50000,128)
    const float* E_targ = (const float*)d_in[7];     // (50000,128)
    const float* W1 = (const float*)d_in[8];         // (128,256)
    const float* b1 = (const float*)d_in[9];         // (128,)
    const float* W2 = (const float*)d_in[10];        // (1,128)
    float* out = (float*)d_out;                      // (4096,)

    unsigned char* W1s = (unsigned char*)d_ws;                   // 32 KB
    unsigned char* histT = W1s + 32768;                          // 12.8 MB fp8
    unsigned short* EioT = (unsigned short*)(histT + (size_t)ITEMN * 256); // 12.8 MB f16

    prep_eio<<<(ITEMN * 16) / 256, 256, 0, stream>>>(E_in, E_out, EioT);

    const int tailBlocks = (int)(((long)ITEMN * 16 + 4096 + 255) / 256);
    regions3<<<RBLK + tailBlocks, 256, 0, stream>>>(
        near_pois, EioT, E_hist, W1, histT, W1s);

    score_kernel<<<NBATCH, 256, 0, stream>>>(
        history, target, histT, E_targ, W1s, b1, W2, out);
}